// Round 15
// baseline (7497.092 us; speedup 1.0000x reference)
//
#include <hip/hip_runtime.h>
#include <math.h>

#define T_STEPS 128
#define BATCH   512
#define NTOK    512
#define NINP    512
#define NHID    600
#define NBK     6
#define BS      100
#define HH      4
#define DK      64
#define DV      85
#define ATT     340
#define H2      4
#define DK2     32
#define DV2     32
#define G3      300
#define VN      340
#define KAPN    400
#define CN      740
#define CNP     768
#define UN2     1800     // merged U cols per head (6 blocks x 300)
#define UN2P    1920     // padded to 15*128
#define UK0     128
#define KV0     512
#define DECKP   640

typedef __attribute__((ext_vector_type(8))) short short8;
typedef __attribute__((ext_vector_type(4))) short short4v;
typedef __attribute__((ext_vector_type(4))) float f32x4;

typedef __attribute__((address_space(1))) const unsigned int* g1ptr;
typedef __attribute__((address_space(3))) unsigned int* l3ptr;

__device__ __forceinline__ float sigf(float x) { return 1.f / (1.f + expf(-x)); }
__device__ __forceinline__ unsigned short f2b(float f) {
    unsigned u = __float_as_uint(f);
    unsigned r = (u + 0x7fffu + ((u >> 16) & 1u)) >> 16;
    return (unsigned short)r;
}
__device__ __forceinline__ float b2f(unsigned short u) {
    return __uint_as_float(((unsigned)u) << 16);
}
__device__ __forceinline__ void split3(float x, unsigned short& hi,
                                       unsigned short& mid, unsigned short& lo) {
    hi = f2b(x);
    float r1 = x - b2f(hi);
    mid = f2b(r1);
    lo = f2b(r1 - b2f(mid));
}

struct ZOff { int div; long s1; long s2; };
__device__ __forceinline__ long zoff(ZOff z, int bz) {
    return (long)(bz / z.div) * z.s1 + (long)(bz % z.div) * z.s2;
}

// Stage a 128x64-short tile into LDS via async global_load_lds (16B/lane).
__device__ __forceinline__ void stage_tile(const unsigned short* __restrict__ gbase,
                                           long rowStride, int m0, int k0,
                                           unsigned short* lds, int tid)
{
    const int w = tid >> 6;
#pragma unroll
    for (int q = 0; q < 4; q++) {
        int idx = (q << 8) + tid;
        int r = idx >> 3, ce = (idx & 7) << 3;
        const unsigned short* g = gbase + (long)(m0 + r) * rowStride + k0 + ce;
        unsigned short* l = lds + q * 2048 + w * 512;   // wave-uniform base
        __builtin_amdgcn_global_load_lds((g1ptr)(const void*)g, (l3ptr)(void*)l, 16, 0, 0);
    }
}
// 64-row variant (2 rounds)
__device__ __forceinline__ void stage_tile64(const unsigned short* __restrict__ gbase,
                                             long rowStride, int m0, int k0,
                                             unsigned short* lds, int tid)
{
    const int w = tid >> 6;
#pragma unroll
    for (int q = 0; q < 2; q++) {
        int idx = (q << 8) + tid;
        int r = idx >> 3, ce = (idx & 7) << 3;
        const unsigned short* g = gbase + (long)(m0 + r) * rowStride + k0 + ce;
        unsigned short* l = lds + q * 2048 + w * 512;
        __builtin_amdgcn_global_load_lds((g1ptr)(const void*)g, (l3ptr)(void*)l, 16, 0, 0);
    }
}

// ===== bf16x6 MFMA GEMM (128x128 tile): fp32-class C = A@B^T (+bias), 6 passes =====
__global__ __launch_bounds__(256) void gemm6(
    const unsigned short* __restrict__ A, long aZ, int aZdiv,
    const unsigned short* __restrict__ B, long bZ,
    float* __restrict__ C, long cZ, int ldc, int Nreal,
    const float* __restrict__ bias, int K0)
{
    const int bz = blockIdx.z;
    A += (long)(bz / aZdiv) * aZ;
    B += (long)bz * bZ;
    C += (long)bz * cZ;
    const int LDA = 3 * K0;
    const int m0 = blockIdx.y * 128, n0 = blockIdx.x * 128;
    __shared__ __align__(16) unsigned short As[128 * 64];
    __shared__ __align__(16) unsigned short Bs[128 * 64];
    const int tid = threadIdx.x;
    const int lane = tid & 63;
    const int wid = tid >> 6;
    const int wr = wid >> 1, wc = wid & 1;

    f32x4 acc[4][4];
#pragma unroll
    for (int m = 0; m < 4; m++)
#pragma unroll
        for (int n = 0; n < 4; n++)
#pragma unroll
            for (int v = 0; v < 4; v++) acc[m][n][v] = 0.f;

    const int segA[6] = {0, 0, 1, 0, 2, 1};
    const int segB[6] = {0, 1, 0, 2, 0, 1};
    for (int p = 0; p < 6; p++) {
        const unsigned short* Ap = A + segA[p] * K0;
        const unsigned short* Bp = B + segB[p] * K0;
        for (int k0 = 0; k0 < K0; k0 += 64) {
            __syncthreads();
            stage_tile(Ap, LDA, m0, k0, As, tid);
            stage_tile(Bp, LDA, n0, k0, Bs, tid);
            __syncthreads();
#pragma unroll
            for (int kk = 0; kk < 2; kk++) {
                short8 af[4], bfr[4];
#pragma unroll
                for (int m = 0; m < 4; m++)
                    af[m] = *(const short8*)&As[(wr * 64 + m * 16 + (lane & 15)) * 64 + kk * 32 + (lane >> 4) * 8];
#pragma unroll
                for (int n = 0; n < 4; n++)
                    bfr[n] = *(const short8*)&Bs[(wc * 64 + n * 16 + (lane & 15)) * 64 + kk * 32 + (lane >> 4) * 8];
#pragma unroll
                for (int m = 0; m < 4; m++)
#pragma unroll
                    for (int n = 0; n < 4; n++)
                        acc[m][n] = __builtin_amdgcn_mfma_f32_16x16x32_bf16(af[m], bfr[n], acc[m][n], 0, 0, 0);
            }
        }
    }
#pragma unroll
    for (int m = 0; m < 4; m++) {
        int rbase = m0 + wr * 64 + m * 16 + (lane >> 4) * 4;
#pragma unroll
        for (int n = 0; n < 4; n++) {
            int col = n0 + wc * 64 + n * 16 + (lane & 15);
            if (col < Nreal) {
                float bv = bias ? bias[col] : 0.f;
#pragma unroll
                for (int v = 0; v < 4; v++)
                    C[(long)(rbase + v) * ldc + col] = acc[m][n][v] + bv;
            }
        }
    }
}

// ===== kv-variant, 64x128 tile -> 384 blocks =====
__global__ __launch_bounds__(256) void gemm6_kv64(
    const unsigned short* __restrict__ A,
    const unsigned short* __restrict__ B,
    unsigned short* __restrict__ A_U,       // [4][MU][3*UK0]
    float* __restrict__ Kbuf,               // [MU][400]
    const float* __restrict__ bias, int K0, int MU)
{
    const int LDA = 3 * K0;
    const int m0 = blockIdx.y * 64, n0 = blockIdx.x * 128;
    __shared__ __align__(16) unsigned short As[64 * 64];
    __shared__ __align__(16) unsigned short Bs[128 * 64];
    const int tid = threadIdx.x;
    const int lane = tid & 63;
    const int w = tid >> 6;

    f32x4 acc[4][2];
#pragma unroll
    for (int m = 0; m < 4; m++)
#pragma unroll
        for (int n = 0; n < 2; n++)
#pragma unroll
            for (int v = 0; v < 4; v++) acc[m][n][v] = 0.f;

    const int segA[6] = {0, 0, 1, 0, 2, 1};
    const int segB[6] = {0, 1, 0, 2, 0, 1};
    for (int p = 0; p < 6; p++) {
        const unsigned short* Ap = A + segA[p] * K0;
        const unsigned short* Bp = B + segB[p] * K0;
        for (int k0 = 0; k0 < K0; k0 += 64) {
            __syncthreads();
            stage_tile64(Ap, LDA, m0, k0, As, tid);
            stage_tile(Bp, LDA, n0, k0, Bs, tid);
            __syncthreads();
#pragma unroll
            for (int kk = 0; kk < 2; kk++) {
                short8 af[4], bfr[2];
#pragma unroll
                for (int m = 0; m < 4; m++)
                    af[m] = *(const short8*)&As[(m * 16 + (lane & 15)) * 64 + kk * 32 + (lane >> 4) * 8];
#pragma unroll
                for (int n = 0; n < 2; n++)
                    bfr[n] = *(const short8*)&Bs[(w * 32 + n * 16 + (lane & 15)) * 64 + kk * 32 + (lane >> 4) * 8];
#pragma unroll
                for (int m = 0; m < 4; m++)
#pragma unroll
                    for (int n = 0; n < 2; n++)
                        acc[m][n] = __builtin_amdgcn_mfma_f32_16x16x32_bf16(af[m], bfr[n], acc[m][n], 0, 0, 0);
            }
        }
    }
#pragma unroll
    for (int m = 0; m < 4; m++) {
        int rbase = m0 + m * 16 + (lane >> 4) * 4;
#pragma unroll
        for (int n = 0; n < 2; n++) {
            int col = n0 + w * 32 + n * 16 + (lane & 15);
            if (col < CN) {
                float bv = bias[col];
                if (col < VN) {
                    int h = col / DV, kk2 = col - h * DV;
#pragma unroll
                    for (int v = 0; v < 4; v++) {
                        float val = acc[m][n][v] + bv;
                        unsigned short hi, mid, lo;
                        split3(val, hi, mid, lo);
                        long base = ((long)h * MU + (rbase + v)) * (3 * UK0) + kk2;
                        A_U[base] = hi;
                        A_U[base + UK0] = mid;
                        A_U[base + 2 * UK0] = lo;
                    }
                } else {
                    int kc = col - VN;
#pragma unroll
                    for (int v = 0; v < 4; v++)
                        Kbuf[(long)(rbase + v) * KAPN + kc] = acc[m][n][v] + bv;
                }
            }
        }
    }
}

// ===== plain bf16 MFMA GEMM, 64x128 tile (decoder) =====
__global__ __launch_bounds__(256) void gemm_mfma64(
    const unsigned short* __restrict__ A,
    const unsigned short* __restrict__ B,
    float* __restrict__ C, int ldc,
    const float* __restrict__ bias, int Kp)
{
    const int m0 = blockIdx.y * 64, n0 = blockIdx.x * 128;
    __shared__ __align__(16) unsigned short As[64 * 64];
    __shared__ __align__(16) unsigned short Bs[128 * 64];
    const int tid = threadIdx.x;
    const int lane = tid & 63;
    const int w = tid >> 6;

    f32x4 acc[4][2];
#pragma unroll
    for (int m = 0; m < 4; m++)
#pragma unroll
        for (int n = 0; n < 2; n++)
#pragma unroll
            for (int v = 0; v < 4; v++) acc[m][n][v] = 0.f;

    for (int k0 = 0; k0 < Kp; k0 += 64) {
        __syncthreads();
        stage_tile64(A, Kp, m0, k0, As, tid);
        stage_tile(B, Kp, n0, k0, Bs, tid);
        __syncthreads();
#pragma unroll
        for (int kk = 0; kk < 2; kk++) {
            short8 af[4], bfr[2];
#pragma unroll
            for (int m = 0; m < 4; m++)
                af[m] = *(const short8*)&As[(m * 16 + (lane & 15)) * 64 + kk * 32 + (lane >> 4) * 8];
#pragma unroll
            for (int n = 0; n < 2; n++)
                bfr[n] = *(const short8*)&Bs[(w * 32 + n * 16 + (lane & 15)) * 64 + kk * 32 + (lane >> 4) * 8];
#pragma unroll
            for (int m = 0; m < 4; m++)
#pragma unroll
                for (int n = 0; n < 2; n++)
                    acc[m][n] = __builtin_amdgcn_mfma_f32_16x16x32_bf16(af[m], bfr[n], acc[m][n], 0, 0, 0);
        }
    }
#pragma unroll
    for (int m = 0; m < 4; m++) {
        int rbase = m0 + m * 16 + (lane >> 4) * 4;
#pragma unroll
        for (int n = 0; n < 2; n++) {
            int col = n0 + w * 32 + n * 16 + (lane & 15);
            float bv = bias ? bias[col] : 0.f;
#pragma unroll
            for (int v = 0; v < 4; v++)
                C[(long)(rbase + v) * ldc + col] = acc[m][n][v] + bv;
        }
    }
}

// ===== fp32 SGEMM (setup-only small jobs) =====
__global__ __launch_bounds__(256) void sgemm(
    const float* __restrict__ A, ZOff za, int lda,
    const float* __restrict__ B, ZOff zb, int ldb,
    float* __restrict__ C, ZOff zc, int ldc,
    int M, int N, int K)
{
    const int bz = blockIdx.z;
    A += zoff(za, bz);
    B += zoff(zb, bz);
    C += zoff(zc, bz);
    const int m0 = blockIdx.y * 128, n0 = blockIdx.x * 64;
    __shared__ float As[16][132];
    __shared__ float Bs[16][68];
    const int tid = threadIdx.x;
    const int tm = tid >> 4, tn = tid & 15;
    const int ar = tid >> 1, ak = (tid & 1) * 8;
    const int bk = tid >> 4, bn = (tid & 15) * 4;

    float acc[8][4];
#pragma unroll
    for (int i = 0; i < 8; i++)
#pragma unroll
        for (int j = 0; j < 4; j++) acc[i][j] = 0.f;

    for (int k0 = 0; k0 < K; k0 += 16) {
        float av[8], bv[4];
#pragma unroll
        for (int j = 0; j < 8; j++) {
            int gk = k0 + ak + j;
            av[j] = (gk < K) ? A[(long)(m0 + ar) * lda + gk] : 0.f;
        }
#pragma unroll
        for (int j = 0; j < 4; j++) {
            int gk = k0 + bk, gn = n0 + bn + j;
            bv[j] = (gk < K && gn < N) ? B[(long)gk * ldb + gn] : 0.f;
        }
        __syncthreads();
#pragma unroll
        for (int j = 0; j < 8; j++) As[ak + j][ar] = av[j];
#pragma unroll
        for (int j = 0; j < 4; j++) Bs[bk][bn + j] = bv[j];
        __syncthreads();
#pragma unroll
        for (int kk = 0; kk < 16; kk++) {
            float a[8], b[4];
#pragma unroll
            for (int i = 0; i < 8; i++) a[i] = As[kk][tm * 8 + i];
#pragma unroll
            for (int j = 0; j < 4; j++) b[j] = Bs[kk][tn * 4 + j];
#pragma unroll
            for (int i = 0; i < 8; i++)
#pragma unroll
                for (int j = 0; j < 4; j++)
                    acc[i][j] += a[i] * b[j];
        }
    }
#pragma unroll
    for (int i = 0; i < 8; i++) {
        int gm = m0 + tm * 8 + i;
#pragma unroll
        for (int j = 0; j < 4; j++) {
            int gn = n0 + tn * 4 + j;
            if (gn < N) C[(long)gm * ldc + gn] = acc[i][j];
        }
    }
}

// ===== prep kernels =====
__global__ __launch_bounds__(256) void prep_wqt(const float* __restrict__ Wq_in,
                                                float* __restrict__ WqT)
{
    int idx = blockIdx.x * 256 + threadIdx.x;
    if (idx >= HH * DK * BS) return;
    int h = idx / (DK * BS), r = idx - h * DK * BS, d = r / BS, w = r - d * BS;
    WqT[idx] = Wq_in[w * (HH * DK) + h * DK + d];
}

// W_hh[n][d][g*100+w] -> Whh4[n][d][w][4]
__global__ __launch_bounds__(256) void prep_whh4(const float* __restrict__ W_hh,
                                                 float* __restrict__ Whh4)
{
    int idx = blockIdx.x * 256 + threadIdx.x;
    if (idx >= NBK * BS * G3) return;
    int n = idx / (BS * G3), r = idx - n * (BS * G3);
    int d = r / G3, e = r - d * G3;
    int g = e / BS, w = e - g * BS;
    Whh4[(((long)n * BS + d) * BS + w) * 4 + g] = W_hh[idx];
}

__global__ __launch_bounds__(256) void bias_k(const float* __restrict__ enc_b,
                                              const float* __restrict__ Wk,
                                              float* __restrict__ kbf)
{
    int j = threadIdx.x;
    if (j >= HH * DK) return;
    float acc = 0.f;
    for (int d = 0; d < NINP; d++) acc += enc_b[d] * Wk[d * (HH * DK) + j];
    kbf[j] = acc;
}

__global__ __launch_bounds__(256) void bias_c_kernel(const float* __restrict__ enc_b,
                                                     const float* __restrict__ Wv,
                                                     const float* __restrict__ kbf,
                                                     const float* __restrict__ WqT,
                                                     float* __restrict__ bias_c)
{
    int j = blockIdx.x * 256 + threadIdx.x;
    if (j >= CNP) return;
    float acc = 0.f;
    if (j < VN) {
        for (int d = 0; d < NINP; d++) acc += enc_b[d] * Wv[d * (HH * DV) + j];
    } else if (j < CN) {
        int r = j - VN;
        int h = r / BS, w = r - h * BS;
        for (int d = 0; d < DK; d++)
            acc += kbf[h * DK + d] * WqT[(h * DK + d) * BS + w];
    }
    bias_c[j] = acc;
}

__global__ __launch_bounds__(256) void cvt_dec(const float* __restrict__ dec_W,
                                               unsigned short* __restrict__ dst)
{
    int idx = blockIdx.x * 256 + threadIdx.x;
    if (idx >= NTOK * DECKP) return;
    int n = idx / DECKP, k = idx - n * DECKP;
    dst[idx] = f2b(k < NHID ? dec_W[k * NTOK + n] : 0.f);
}

__global__ __launch_bounds__(256) void cvt_split_ew(const float* __restrict__ EWfull,
                                                    unsigned short* __restrict__ dst)
{
    int idx = blockIdx.x * 256 + threadIdx.x;
    if (idx >= CNP * NTOK) return;
    int n = idx / NTOK, k = idx - n * NTOK;
    float x = (n < CN) ? EWfull[(long)k * CNP + n] : 0.f;
    unsigned short hi, mid, lo;
    split3(x, hi, mid, lo);
    long base = (long)n * (3 * KV0) + k;
    dst[base] = hi;
    dst[base + KV0] = mid;
    dst[base + 2 * KV0] = lo;
}

// W_ih -> B_U2: [4][1920][3*128]; col j = n*300 + e
__global__ __launch_bounds__(256) void cvt_split_bu2(const float* __restrict__ W_ih,
                                                     unsigned short* __restrict__ dst)
{
    int idx = blockIdx.x * 256 + threadIdx.x;
    if (idx >= HH * UN2P * UK0) return;
    int h = idx / (UN2P * UK0), r = idx - h * (UN2P * UK0);
    int j = r / UK0, kk = r - j * UK0;
    float x = 0.f;
    if (kk < DV && j < UN2) {
        int n = j / G3, e = j - n * G3;
        x = W_ih[((long)n * ATT + h * DV + kk) * G3 + e];
    }
    unsigned short hi, mid, lo;
    split3(x, hi, mid, lo);
    long base = ((long)h * UN2P + j) * (3 * UK0) + kk;
    dst[base] = hi;
    dst[base + UK0] = mid;
    dst[base + 2 * UK0] = lo;
}

// vectorized: f32x4 read, short4 writes per segment
__global__ __launch_bounds__(256) void cvt_split_in(const float* __restrict__ src,
                                                    unsigned short* __restrict__ dst, long rows)
{
    long total = rows * (NTOK / 4);
    long i = (long)blockIdx.x * 256 + threadIdx.x;
    long stride = (long)gridDim.x * 256;
    for (; i < total; i += stride) {
        long row = i / (NTOK / 4);
        int k4 = (int)(i - row * (NTOK / 4)) * 4;
        f32x4 x = *(const f32x4*)&src[row * NTOK + k4];
        short4v hi, mid, lo;
#pragma unroll
        for (int j = 0; j < 4; j++) {
            unsigned short h, m, l;
            split3(x[j], h, m, l);
            hi[j] = (short)h; mid[j] = (short)m; lo[j] = (short)l;
        }
        long base = row * (3 * KV0) + k4;
        *(short4v*)&dst[base] = hi;
        *(short4v*)&dst[base + KV0] = mid;
        *(short4v*)&dst[base + 2 * KV0] = lo;
    }
}

// ===== step kernel v8: SW=1, 512 threads, grid 512 -> 2 blocks/CU =====
__global__ __launch_bounds__(512) void step_fused(
    const float* __restrict__ h_prev,       // [512,600]
    const float* __restrict__ masks_t,      // [512]
    const float* __restrict__ Kbuf,         // [MU,400]
    const float* __restrict__ U,            // [4,MU,1800]
    const float* __restrict__ b_ih, const float* __restrict__ b_hh,
    const float* __restrict__ Whh4,         // [6][100][100][4]
    const float* __restrict__ Wq_c, const float* __restrict__ Wk_c,
    const float* __restrict__ Wv_c, const float* __restrict__ Wo_c,
    float* __restrict__ h_out,              // [512,600]
    unsigned short* __restrict__ A_dec,     // [MU,640] bf16
    int s_step, int MU)
{
    const int b = blockIdx.x, tid = threadIdx.x;
    __shared__ __align__(16) float hb[NHID];
    __shared__ __align__(16) float hn[NHID];
    __shared__ __align__(16) float kp[KAPN];
    __shared__ __align__(16) float qcb[768], kcb[768], vcb[768];
    __shared__ __align__(16) float co[768];
    __shared__ float part[96];
    __shared__ float att[24], mk[NBK];
    __shared__ float lg[144];

    const long rowd = (long)s_step * BATCH + b;
    // pass-A / pass-B output indices for 600-wide phases
    const int oA = tid;                     // always < 600 (512 < 600)
    const int nA = oA / 100, wA = oA - nA * 100;
    const bool hasB = tid < 88;
    const int oB = tid + 512;
    const int nB = oB / 100, wB = oB - nB * 100;

    // ---- EARLY ISSUE: U gathers (consumed in P2) ----
    float urA[HH][3], urB[HH][3];
    {
        const float* Ub = U + rowd * UN2;
#pragma unroll
        for (int h = 0; h < HH; h++) {
            const float* Uh = Ub + (long)h * MU * UN2;
#pragma unroll
            for (int g = 0; g < 3; g++)
                urA[h][g] = Uh[nA * G3 + g * BS + wA];
        }
        if (hasB) {
#pragma unroll
            for (int h = 0; h < HH; h++) {
                const float* Uh = Ub + (long)h * MU * UN2;
#pragma unroll
                for (int g = 0; g < 3; g++)
                    urB[h][g] = Uh[nB * G3 + g * BS + wB];
            }
        }
    }

    // ---- P0: load state + kappa ----
    const float mt = masks_t[b];
    for (int i = tid; i < NHID; i += 512) hb[i] = h_prev[(long)b * NHID + i] * mt;
    if (tid >= 512 - KAPN || true) {
        for (int i = tid; i < KAPN; i += 512) kp[i] = Kbuf[rowd * KAPN + i];
    }
    __syncthreads();
    // ---- P1: input-attention logits (24 x 4 quarters) ----
    if (tid < 96) {
        int r = tid >> 2, q = tid & 3;      // r = n*4+h
        int n = r >> 2, h = r & 3;
        float acc = 0.f;
        int w0 = q * 25;
        for (int w = w0; w < w0 + 25; w++) acc += hb[n * BS + w] * kp[h * BS + w];
        part[tid] = acc;
    }
    __syncthreads();
    if (tid < 24) {
        float l = part[tid * 4] + part[tid * 4 + 1] + part[tid * 4 + 2] + part[tid * 4 + 3];
        att[tid] = sigf(l * 0.125f);        // softmax([l,0])[0] == sigmoid(l)
    }
    __syncthreads();
    if (tid == 0) {
        float a[NBK], av[NBK];
        for (int n = 0; n < NBK; n++) {
            av[n] = 0.25f * (att[n * 4] + att[n * 4 + 1] + att[n * 4 + 2] + att[n * 4 + 3]);
            a[n] = av[n];
        }
        for (int i = 0; i < 4; i++) {
            int mx = i;
            for (int j = i + 1; j < NBK; j++) if (a[j] > a[mx]) mx = j;
            float t = a[i]; a[i] = a[mx]; a[mx] = t;
        }
        float kth = a[3];
        for (int n = 0; n < NBK; n++) mk[n] = (av[n] >= kth) ? 1.f : 0.f;
    }

    // ---- P2: GRU (two passes: oA for all, oB for tid<88) ----
    {
        // pass A
        float gi0 = b_ih[nA * G3 + wA], gi1 = b_ih[nA * G3 + BS + wA], gi2 = b_ih[nA * G3 + 2 * BS + wA];
        float gh0 = b_hh[nA * G3 + wA], gh1 = b_hh[nA * G3 + BS + wA], gh2 = b_hh[nA * G3 + 2 * BS + wA];
#pragma unroll
        for (int h = 0; h < HH; h++) {
            float a = att[nA * 4 + h];
            gi0 += a * urA[h][0];
            gi1 += a * urA[h][1];
            gi2 += a * urA[h][2];
        }
        float gj0 = 0.f, gj1 = 0.f, gj2 = 0.f;   // pass B accumulators
        if (hasB) {
            gj0 = b_hh[nB * G3 + wB]; gj1 = b_hh[nB * G3 + BS + wB]; gj2 = b_hh[nB * G3 + 2 * BS + wB];
        }
        const f32x4* WA = ((const f32x4*)Whh4) + (long)nA * BS * BS + wA;
        const f32x4* WB = ((const f32x4*)Whh4) + (long)nB * BS * BS + wB;
#pragma unroll 10
        for (int d = 0; d < BS; d++) {
            f32x4 wv = WA[(long)d * BS];
            float hv = hb[nA * BS + d];
            gh0 += wv[0] * hv;
            gh1 += wv[1] * hv;
            gh2 += wv[2] * hv;
        }
        if (hasB) {
#pragma unroll 10
            for (int d = 0; d < BS; d++) {
                f32x4 wv = WB[(long)d * BS];
                float hv = hb[nB * BS + d];
                gj0 += wv[0] * hv;
                gj1 += wv[1] * hv;
                gj2 += wv[2] * hv;
            }
        }
        {
            float rr = sigf(gi0 + gh0);
            float zz = sigf(gi1 + gh1);
            float ng = tanhf(gi2 + rr * gh2);
            hn[oA] = (1.f - zz) * ng + zz * hb[oA];
        }
        if (hasB) {
            float fi0 = b_ih[nB * G3 + wB], fi1 = b_ih[nB * G3 + BS + wB], fi2 = b_ih[nB * G3 + 2 * BS + wB];
#pragma unroll
            for (int h = 0; h < HH; h++) {
                float a = att[nB * 4 + h];
                fi0 += a * urB[h][0];
                fi1 += a * urB[h][1];
                fi2 += a * urB[h][2];
            }
            float rr = sigf(fi0 + gj0);
            float zz = sigf(fi1 + gj1);
            float ng = tanhf(fi2 + rr * gj2);
            hn[oB] = (1.f - zz) * ng + zz * hb[oB];
        }
    }
    __syncthreads();

    // ---- P3: comm projections (768 outputs: pass A 512 + pass B 256) ----
    {
        // pass A: o = tid -> mat = tid>>8 (0 or 1), ng = (tid>>7)&1, c = tid&127
        const int matA = tid >> 8, ngA = (tid >> 7) & 1, cA = tid & 127;
        const float* Wa = (matA == 0) ? Wq_c : Wk_c;
        float accA3[3] = {0.f, 0.f, 0.f};
        // pass B (tid<256): mat=2 (Wv), ng = tid>>7, c = tid&127
        const bool hasB3 = tid < 256;
        const int ngB = tid >> 7, cB = tid & 127;
        float accB3[3] = {0.f, 0.f, 0.f};
#pragma unroll 10
        for (int d = 0; d < BS; d++) {
            float wv = Wa[d * 128 + cA];
#pragma unroll
            for (int j = 0; j < 3; j++)
                accA3[j] += wv * hn[(ngA * 3 + j) * BS + d];
        }
        if (hasB3) {
#pragma unroll 10
            for (int d = 0; d < BS; d++) {
                float wv = Wv_c[d * 128 + cB];
#pragma unroll
                for (int j = 0; j < 3; j++)
                    accB3[j] += wv * hn[(ngB * 3 + j) * BS + d];
            }
        }
        float* dstA = (matA == 0) ? qcb : kcb;
#pragma unroll
        for (int j = 0; j < 3; j++)
            dstA[(ngA * 3 + j) * 128 + cA] = accA3[j];
        if (hasB3) {
#pragma unroll
            for (int j = 0; j < 3; j++)
                vcb[(ngB * 3 + j) * 128 + cB] = accB3[j];
        }
    }
    __syncthreads();

    // ---- P4: comm attention logits + softmax + co ----
    if (tid < 144) {
        int h = tid / 36, r2 = tid - h * 36, n = r2 / NBK, m = r2 - n * NBK;
        float sv = 0.f;
#pragma unroll
        for (int e4 = 0; e4 < 8; e4++) {
            f32x4 qv = *(const f32x4*)&qcb[n * 128 + h * 32 + e4 * 4];
            f32x4 kv = *(const f32x4*)&kcb[m * 128 + h * 32 + e4 * 4];
            sv += qv[0] * kv[0] + qv[1] * kv[1] + qv[2] * kv[2] + qv[3] * kv[3];
        }
        lg[tid] = sv * 0.17677669529663687f;
    }
    __syncthreads();
    if (tid < 24) {
        int h = tid / NBK, n = tid - h * NBK;
        float* row = &lg[h * 36 + n * NBK];
        float mx = row[0];
        for (int m = 1; m < NBK; m++) mx = fmaxf(mx, row[m]);
        float sv = 0.f;
        for (int m = 0; m < NBK; m++) { row[m] = expf(row[m] - mx); sv += row[m]; }
        float inv = 1.f / sv;
        for (int m = 0; m < NBK; m++) row[m] *= inv;
    }
    __syncthreads();
    {
        // co: 768 outputs = pass A (512) + pass B (256)
        int r = tid;
        int n = r >> 7, d = r & 127, h = d >> 5;
        float a = 0.f;
#pragma unroll
        for (int m = 0; m < NBK; m++) a += lg[h * 36 + n * NBK + m] * vcb[m * 128 + d];
        co[r] = a;
        if (tid < 256) {
            int r2 = tid + 512;
            int n2 = r2 >> 7, d2 = r2 & 127, h2 = d2 >> 5;
            float a2 = 0.f;
#pragma unroll
            for (int m = 0; m < NBK; m++) a2 += lg[h2 * 36 + n2 * NBK + m] * vcb[m * 128 + d2];
            co[r2] = a2;
        }
    }
    __syncthreads();

    // ---- P5: co @ Wo_c + masked select (two passes) ----
    {
        float a0 = 0.f, a1 = 0.f;
#pragma unroll 8
        for (int d = 0; d < 128; d++) {
            float cvA = co[nA * 128 + d];
            a0 += Wo_c[d * BS + wA] * cvA;
        }
        if (hasB) {
#pragma unroll 8
            for (int d = 0; d < 128; d++) {
                float cvB = co[nB * 128 + d];
                a1 += Wo_c[d * BS + wB] * cvB;
            }
        }
        float hcA = hn[oA] + a0;
        float resA = (mk[nA] > 0.5f) ? hcA : hb[oA];
        float resB = 0.f;
        if (hasB) {
            float hcB = hn[oB] + a1;
            resB = (mk[nB] > 0.5f) ? hcB : hb[oB];
        }
        __syncthreads();                     // all reads of hb/hn done
        hb[oA] = resA;                       // reuse hb as output staging
        if (hasB) hb[oB] = resB;
    }
    __syncthreads();
    // ---- P6: coalesced global writes ----
    for (int i = tid; i < NHID; i += 512)
        h_out[(long)b * NHID + i] = hb[i];
    for (int i = tid; i < DECKP; i += 512)
        A_dec[rowd * DECKP + i] = f2b(i < NHID ? hb[i] : 0.f);
}

// ===== host launch =====
extern "C" void kernel_launch(void* const* d_in, const int* in_sizes, int n_in,
                              void* d_out, int out_size, void* d_ws, size_t ws_size,
                              hipStream_t stream)
{
    const float* input = (const float*)d_in[0];
    const float* h0    = (const float*)d_in[1];
    const float* masks = (const float*)d_in[2];
    const float* enc_W = (const float*)d_in[3];
    const float* enc_b = (const float*)d_in[4];
    const float* Wq_in = (const float*)d_in[5];
    const float* Wk_in = (const float*)d_in[6];
    const float* Wv_in = (const float*)d_in[7];
    const float* W_ih  = (const float*)d_in[8];
    const float* W_hh  = (const float*)d_in[9];
    const float* b_ih  = (const float*)d_in[10];
    const float* b_hh  = (const float*)d_in[11];
    const float* Wq_c  = (const float*)d_in[12];
    const float* Wk_c  = (const float*)d_in[13];
    const float* Wv_c  = (const float*)d_in[14];
    const float* Wo_c  = (const float*)d_in[15];
    const float* dec_W = (const float*)d_in[16];
    const float* dec_b = (const float*)d_in[17];
    float* out = (float*)d_out;

    const size_t AL = 256;
    auto pad = [&](size_t x) { return (x + AL - 1) & ~(AL - 1); };
    size_t fixedB = pad((size_t)NTOK * CNP * 4)
                  + pad((size_t)NTOK * 256 * 4)
                  + pad((size_t)HH * DK * BS * 4)
                  + pad((size_t)256 * 4)
                  + pad((size_t)CNP * 4)
                  + pad((size_t)NBK * BS * BS * 4 * 4)     // Whh4
                  + pad((size_t)CNP * 3 * KV0 * 2)
                  + pad((size_t)HH * UN2P * 3 * UK0 * 2)
                  + pad((size_t)NTOK * DECKP * 2)
                  + 2 * pad((size_t)BATCH * NHID * 4);
    auto perC = [&](int C) {
        size_t MU = (size_t)C * BATCH;
        return pad(MU * 3 * KV0 * 2)
             + pad(MU * KAPN * 4)
             + pad((size_t)HH * MU * 3 * UK0 * 2)
             + pad((size_t)HH * MU * UN2 * 4)
             + pad(MU * DECKP * 2);
    };
    int C = 8;
    while (C > 1 && fixedB + perC(C) > ws_size) C >>= 1;
    const int MU = C * BATCH;
    const int NCH = T_STEPS / C;

    char* p = (char*)d_ws;
    auto alloc = [&](size_t bytes) { char* r = p; p += pad(bytes); return r; };
    float*          EWfull = (float*)alloc((size_t)NTOK * CNP * 4);
    float*          EWk    = (float*)alloc((size_t)NTOK * 256 * 4);
    float*          WqT    = (float*)alloc((size_t)HH * DK * BS * 4);
    float*          kbf    = (float*)alloc((size_t)256 * 4);
    float*          bias_c = (float*)alloc((size_t)CNP * 4);
    float*          Whh4   = (float*)alloc((size_t)NBK * BS * BS * 4 * 4);
    unsigned short* B_vkap = (unsigned short*)alloc((size_t)CNP * 3 * KV0 * 2);
    unsigned short* B_U    = (unsigned short*)alloc((size_t)HH * UN2P * 3 * UK0 * 2);
    unsigned short* B_dec  = (unsigned short*)alloc((size_t)NTOK * DECKP * 2);
    float*          hA     = (float*)alloc((size_t)BATCH * NHID * 4);
    float*          hB     = (float*)alloc((size_t)BATCH * NHID * 4);
    unsigned short* A_in   = (unsigned short*)alloc((size_t)MU * 3 * KV0 * 2);
    float*          Kbuf   = (float*)alloc((size_t)MU * KAPN * 4);
    unsigned short* A_U    = (unsigned short*)alloc((size_t)HH * MU * 3 * UK0 * 2);
    float*          Ubuf   = (float*)alloc((size_t)HH * MU * UN2 * 4);
    unsigned short* A_dec  = (unsigned short*)alloc((size_t)MU * DECKP * 2);

    dim3 blk(256);
    ZOff z0 = {1, 0, 0};

    // ---- setup ----
    sgemm<<<dim3(6, 4, 1), blk, 0, stream>>>(
        enc_W, z0, NINP, Wv_in, z0, HH * DV, EWfull, z0, CNP, NTOK, VN, NINP);
    sgemm<<<dim3(4, 4, 1), blk, 0, stream>>>(
        enc_W, z0, NINP, Wk_in, z0, HH * DK, EWk, z0, 256, NTOK, HH * DK, NINP);
    prep_wqt<<<dim3((HH * DK * BS + 255) / 256), blk, 0, stream>>>(Wq_in, WqT);
    prep_whh4<<<dim3((NBK * BS * G3 + 255) / 256), blk, 0, stream>>>(W_hh, Whh4);
    sgemm<<<dim3(2, 4, HH), blk, 0, stream>>>(
        EWk, ZOff{1, DK, 0}, 256, WqT, ZOff{1, (long)DK * BS, 0}, BS,
        EWfull + VN, ZOff{1, BS, 0}, CNP, NTOK, BS, DK);
    bias_k<<<dim3(1), blk, 0, stream>>>(enc_b, Wk_in, kbf);
    bias_c_kernel<<<dim3(3), blk, 0, stream>>>(enc_b, Wv_in, kbf, WqT, bias_c);
    cvt_split_ew<<<dim3((CNP * NTOK + 255) / 256), blk, 0, stream>>>(EWfull, B_vkap);
    cvt_split_bu2<<<dim3((HH * UN2P * UK0 + 255) / 256), blk, 0, stream>>>(W_ih, B_U);
    cvt_dec<<<dim3((NTOK * DECKP + 255) / 256), blk, 0, stream>>>(dec_W, B_dec);

    const float* hp = h0;
    float* hbufs[2] = { hA, hB };
    int t = 0;
    for (int c = 0; c < NCH; c++) {
        cvt_split_in<<<dim3(2048), blk, 0, stream>>>(
            input + (size_t)c * MU * NTOK, A_in, MU);
        gemm6_kv64<<<dim3(CNP / 128, MU / 64, 1), blk, 0, stream>>>(
            A_in, B_vkap, A_U, Kbuf, bias_c, KV0, MU);
        gemm6<<<dim3(UN2P / 128, MU / 128, HH), blk, 0, stream>>>(
            A_U, (long)MU * 3 * UK0, 1, B_U, (long)UN2P * 3 * UK0,
            Ubuf, (long)MU * UN2, UN2, UN2, nullptr, UK0);
        for (int s = 0; s < C; s++, t++) {
            float* hout = hbufs[t & 1];
            step_fused<<<dim3(BATCH), dim3(512), 0, stream>>>(
                hp, masks + (size_t)t * BATCH, Kbuf, Ubuf, b_ih, b_hh, Whh4,
                Wq_c, Wk_c, Wv_c, Wo_c, hout, A_dec, s, MU);
            hp = hout;
        }
        gemm_mfma64<<<dim3(NTOK / 128, MU / 64, 1), blk, 0, stream>>>(
            A_dec, B_dec, out + (size_t)c * MU * NTOK, NTOK, dec_b, DECKP);
    }
}

// Round 16
// 5998.305 us; speedup vs baseline: 1.2499x; 1.2499x over previous
//
#include <hip/hip_runtime.h>
#include <math.h>

#define T_STEPS 128
#define BATCH   512
#define NTOK    512
#define NINP    512
#define NHID    600
#define NBK     6
#define BS      100
#define HH      4
#define DK      64
#define DV      85
#define ATT     340
#define H2      4
#define DK2     32
#define DV2     32
#define G3      300
#define VN      340
#define KAPN    400
#define CN      740
#define CNP     768
#define UN2     1800     // merged U cols per head (6 blocks x 300)
#define UN2P    1920     // padded to 15*128
#define UK0     128
#define KV0     512
#define DECKP   640
#define SW      2        // samples per step-block -> grid 256 = all CUs (measured optimum R14)

typedef __attribute__((ext_vector_type(8))) short short8;
typedef __attribute__((ext_vector_type(4))) short short4v;
typedef __attribute__((ext_vector_type(4))) float f32x4;

typedef __attribute__((address_space(1))) const unsigned int* g1ptr;
typedef __attribute__((address_space(3))) unsigned int* l3ptr;

__device__ __forceinline__ float sigf(float x) { return 1.f / (1.f + expf(-x)); }
__device__ __forceinline__ unsigned short f2b(float f) {
    unsigned u = __float_as_uint(f);
    unsigned r = (u + 0x7fffu + ((u >> 16) & 1u)) >> 16;
    return (unsigned short)r;
}
__device__ __forceinline__ float b2f(unsigned short u) {
    return __uint_as_float(((unsigned)u) << 16);
}
__device__ __forceinline__ void split3(float x, unsigned short& hi,
                                       unsigned short& mid, unsigned short& lo) {
    hi = f2b(x);
    float r1 = x - b2f(hi);
    mid = f2b(r1);
    lo = f2b(r1 - b2f(mid));
}

struct ZOff { int div; long s1; long s2; };
__device__ __forceinline__ long zoff(ZOff z, int bz) {
    return (long)(bz / z.div) * z.s1 + (long)(bz % z.div) * z.s2;
}

// Stage a 128x64-short tile into LDS via async global_load_lds (16B/lane).
__device__ __forceinline__ void stage_tile(const unsigned short* __restrict__ gbase,
                                           long rowStride, int m0, int k0,
                                           unsigned short* lds, int tid)
{
    const int w = tid >> 6;
#pragma unroll
    for (int q = 0; q < 4; q++) {
        int idx = (q << 8) + tid;
        int r = idx >> 3, ce = (idx & 7) << 3;
        const unsigned short* g = gbase + (long)(m0 + r) * rowStride + k0 + ce;
        unsigned short* l = lds + q * 2048 + w * 512;   // wave-uniform base
        __builtin_amdgcn_global_load_lds((g1ptr)(const void*)g, (l3ptr)(void*)l, 16, 0, 0);
    }
}
// 64-row variant (2 rounds)
__device__ __forceinline__ void stage_tile64(const unsigned short* __restrict__ gbase,
                                             long rowStride, int m0, int k0,
                                             unsigned short* lds, int tid)
{
    const int w = tid >> 6;
#pragma unroll
    for (int q = 0; q < 2; q++) {
        int idx = (q << 8) + tid;
        int r = idx >> 3, ce = (idx & 7) << 3;
        const unsigned short* g = gbase + (long)(m0 + r) * rowStride + k0 + ce;
        unsigned short* l = lds + q * 2048 + w * 512;
        __builtin_amdgcn_global_load_lds((g1ptr)(const void*)g, (l3ptr)(void*)l, 16, 0, 0);
    }
}

// ===== bf16x6 MFMA GEMM (128x128 tile): fp32-class C = A@B^T (+bias), 6 passes =====
__global__ __launch_bounds__(256) void gemm6(
    const unsigned short* __restrict__ A, long aZ, int aZdiv,
    const unsigned short* __restrict__ B, long bZ,
    float* __restrict__ C, long cZ, int ldc, int Nreal,
    const float* __restrict__ bias, int K0)
{
    const int bz = blockIdx.z;
    A += (long)(bz / aZdiv) * aZ;
    B += (long)bz * bZ;
    C += (long)bz * cZ;
    const int LDA = 3 * K0;
    const int m0 = blockIdx.y * 128, n0 = blockIdx.x * 128;
    __shared__ __align__(16) unsigned short As[128 * 64];
    __shared__ __align__(16) unsigned short Bs[128 * 64];
    const int tid = threadIdx.x;
    const int lane = tid & 63;
    const int wid = tid >> 6;
    const int wr = wid >> 1, wc = wid & 1;

    f32x4 acc[4][4];
#pragma unroll
    for (int m = 0; m < 4; m++)
#pragma unroll
        for (int n = 0; n < 4; n++)
#pragma unroll
            for (int v = 0; v < 4; v++) acc[m][n][v] = 0.f;

    const int segA[6] = {0, 0, 1, 0, 2, 1};
    const int segB[6] = {0, 1, 0, 2, 0, 1};
    for (int p = 0; p < 6; p++) {
        const unsigned short* Ap = A + segA[p] * K0;
        const unsigned short* Bp = B + segB[p] * K0;
        for (int k0 = 0; k0 < K0; k0 += 64) {
            __syncthreads();
            stage_tile(Ap, LDA, m0, k0, As, tid);
            stage_tile(Bp, LDA, n0, k0, Bs, tid);
            __syncthreads();
#pragma unroll
            for (int kk = 0; kk < 2; kk++) {
                short8 af[4], bfr[4];
#pragma unroll
                for (int m = 0; m < 4; m++)
                    af[m] = *(const short8*)&As[(wr * 64 + m * 16 + (lane & 15)) * 64 + kk * 32 + (lane >> 4) * 8];
#pragma unroll
                for (int n = 0; n < 4; n++)
                    bfr[n] = *(const short8*)&Bs[(wc * 64 + n * 16 + (lane & 15)) * 64 + kk * 32 + (lane >> 4) * 8];
#pragma unroll
                for (int m = 0; m < 4; m++)
#pragma unroll
                    for (int n = 0; n < 4; n++)
                        acc[m][n] = __builtin_amdgcn_mfma_f32_16x16x32_bf16(af[m], bfr[n], acc[m][n], 0, 0, 0);
            }
        }
    }
#pragma unroll
    for (int m = 0; m < 4; m++) {
        int rbase = m0 + wr * 64 + m * 16 + (lane >> 4) * 4;
#pragma unroll
        for (int n = 0; n < 4; n++) {
            int col = n0 + wc * 64 + n * 16 + (lane & 15);
            if (col < Nreal) {
                float bv = bias ? bias[col] : 0.f;
#pragma unroll
                for (int v = 0; v < 4; v++)
                    C[(long)(rbase + v) * ldc + col] = acc[m][n][v] + bv;
            }
        }
    }
}

// ===== kv-variant, 64x128 tile -> 384 blocks =====
__global__ __launch_bounds__(256) void gemm6_kv64(
    const unsigned short* __restrict__ A,
    const unsigned short* __restrict__ B,
    unsigned short* __restrict__ A_U,       // [4][MU][3*UK0]
    float* __restrict__ Kbuf,               // [MU][400]
    const float* __restrict__ bias, int K0, int MU)
{
    const int LDA = 3 * K0;
    const int m0 = blockIdx.y * 64, n0 = blockIdx.x * 128;
    __shared__ __align__(16) unsigned short As[64 * 64];
    __shared__ __align__(16) unsigned short Bs[128 * 64];
    const int tid = threadIdx.x;
    const int lane = tid & 63;
    const int w = tid >> 6;

    f32x4 acc[4][2];
#pragma unroll
    for (int m = 0; m < 4; m++)
#pragma unroll
        for (int n = 0; n < 2; n++)
#pragma unroll
            for (int v = 0; v < 4; v++) acc[m][n][v] = 0.f;

    const int segA[6] = {0, 0, 1, 0, 2, 1};
    const int segB[6] = {0, 1, 0, 2, 0, 1};
    for (int p = 0; p < 6; p++) {
        const unsigned short* Ap = A + segA[p] * K0;
        const unsigned short* Bp = B + segB[p] * K0;
        for (int k0 = 0; k0 < K0; k0 += 64) {
            __syncthreads();
            stage_tile64(Ap, LDA, m0, k0, As, tid);
            stage_tile(Bp, LDA, n0, k0, Bs, tid);
            __syncthreads();
#pragma unroll
            for (int kk = 0; kk < 2; kk++) {
                short8 af[4], bfr[2];
#pragma unroll
                for (int m = 0; m < 4; m++)
                    af[m] = *(const short8*)&As[(m * 16 + (lane & 15)) * 64 + kk * 32 + (lane >> 4) * 8];
#pragma unroll
                for (int n = 0; n < 2; n++)
                    bfr[n] = *(const short8*)&Bs[(w * 32 + n * 16 + (lane & 15)) * 64 + kk * 32 + (lane >> 4) * 8];
#pragma unroll
                for (int m = 0; m < 4; m++)
#pragma unroll
                    for (int n = 0; n < 2; n++)
                        acc[m][n] = __builtin_amdgcn_mfma_f32_16x16x32_bf16(af[m], bfr[n], acc[m][n], 0, 0, 0);
            }
        }
    }
#pragma unroll
    for (int m = 0; m < 4; m++) {
        int rbase = m0 + m * 16 + (lane >> 4) * 4;
#pragma unroll
        for (int n = 0; n < 2; n++) {
            int col = n0 + w * 32 + n * 16 + (lane & 15);
            if (col < CN) {
                float bv = bias[col];
                if (col < VN) {
                    int h = col / DV, kk2 = col - h * DV;
#pragma unroll
                    for (int v = 0; v < 4; v++) {
                        float val = acc[m][n][v] + bv;
                        unsigned short hi, mid, lo;
                        split3(val, hi, mid, lo);
                        long base = ((long)h * MU + (rbase + v)) * (3 * UK0) + kk2;
                        A_U[base] = hi;
                        A_U[base + UK0] = mid;
                        A_U[base + 2 * UK0] = lo;
                    }
                } else {
                    int kc = col - VN;
#pragma unroll
                    for (int v = 0; v < 4; v++)
                        Kbuf[(long)(rbase + v) * KAPN + kc] = acc[m][n][v] + bv;
                }
            }
        }
    }
}

// ===== plain bf16 MFMA GEMM, 64x128 tile (decoder) =====
__global__ __launch_bounds__(256) void gemm_mfma64(
    const unsigned short* __restrict__ A,
    const unsigned short* __restrict__ B,
    float* __restrict__ C, int ldc,
    const float* __restrict__ bias, int Kp)
{
    const int m0 = blockIdx.y * 64, n0 = blockIdx.x * 128;
    __shared__ __align__(16) unsigned short As[64 * 64];
    __shared__ __align__(16) unsigned short Bs[128 * 64];
    const int tid = threadIdx.x;
    const int lane = tid & 63;
    const int w = tid >> 6;

    f32x4 acc[4][2];
#pragma unroll
    for (int m = 0; m < 4; m++)
#pragma unroll
        for (int n = 0; n < 2; n++)
#pragma unroll
            for (int v = 0; v < 4; v++) acc[m][n][v] = 0.f;

    for (int k0 = 0; k0 < Kp; k0 += 64) {
        __syncthreads();
        stage_tile64(A, Kp, m0, k0, As, tid);
        stage_tile(B, Kp, n0, k0, Bs, tid);
        __syncthreads();
#pragma unroll
        for (int kk = 0; kk < 2; kk++) {
            short8 af[4], bfr[2];
#pragma unroll
            for (int m = 0; m < 4; m++)
                af[m] = *(const short8*)&As[(m * 16 + (lane & 15)) * 64 + kk * 32 + (lane >> 4) * 8];
#pragma unroll
            for (int n = 0; n < 2; n++)
                bfr[n] = *(const short8*)&Bs[(w * 32 + n * 16 + (lane & 15)) * 64 + kk * 32 + (lane >> 4) * 8];
#pragma unroll
            for (int m = 0; m < 4; m++)
#pragma unroll
                for (int n = 0; n < 2; n++)
                    acc[m][n] = __builtin_amdgcn_mfma_f32_16x16x32_bf16(af[m], bfr[n], acc[m][n], 0, 0, 0);
        }
    }
#pragma unroll
    for (int m = 0; m < 4; m++) {
        int rbase = m0 + m * 16 + (lane >> 4) * 4;
#pragma unroll
        for (int n = 0; n < 2; n++) {
            int col = n0 + w * 32 + n * 16 + (lane & 15);
            float bv = bias ? bias[col] : 0.f;
#pragma unroll
            for (int v = 0; v < 4; v++)
                C[(long)(rbase + v) * ldc + col] = acc[m][n][v] + bv;
        }
    }
}

// ===== fp32 SGEMM (setup-only small jobs) =====
__global__ __launch_bounds__(256) void sgemm(
    const float* __restrict__ A, ZOff za, int lda,
    const float* __restrict__ B, ZOff zb, int ldb,
    float* __restrict__ C, ZOff zc, int ldc,
    int M, int N, int K)
{
    const int bz = blockIdx.z;
    A += zoff(za, bz);
    B += zoff(zb, bz);
    C += zoff(zc, bz);
    const int m0 = blockIdx.y * 128, n0 = blockIdx.x * 64;
    __shared__ float As[16][132];
    __shared__ float Bs[16][68];
    const int tid = threadIdx.x;
    const int tm = tid >> 4, tn = tid & 15;
    const int ar = tid >> 1, ak = (tid & 1) * 8;
    const int bk = tid >> 4, bn = (tid & 15) * 4;

    float acc[8][4];
#pragma unroll
    for (int i = 0; i < 8; i++)
#pragma unroll
        for (int j = 0; j < 4; j++) acc[i][j] = 0.f;

    for (int k0 = 0; k0 < K; k0 += 16) {
        float av[8], bv[4];
#pragma unroll
        for (int j = 0; j < 8; j++) {
            int gk = k0 + ak + j;
            av[j] = (gk < K) ? A[(long)(m0 + ar) * lda + gk] : 0.f;
        }
#pragma unroll
        for (int j = 0; j < 4; j++) {
            int gk = k0 + bk, gn = n0 + bn + j;
            bv[j] = (gk < K && gn < N) ? B[(long)gk * ldb + gn] : 0.f;
        }
        __syncthreads();
#pragma unroll
        for (int j = 0; j < 8; j++) As[ak + j][ar] = av[j];
#pragma unroll
        for (int j = 0; j < 4; j++) Bs[bk][bn + j] = bv[j];
        __syncthreads();
#pragma unroll
        for (int kk = 0; kk < 16; kk++) {
            float a[8], b[4];
#pragma unroll
            for (int i = 0; i < 8; i++) a[i] = As[kk][tm * 8 + i];
#pragma unroll
            for (int j = 0; j < 4; j++) b[j] = Bs[kk][tn * 4 + j];
#pragma unroll
            for (int i = 0; i < 8; i++)
#pragma unroll
                for (int j = 0; j < 4; j++)
                    acc[i][j] += a[i] * b[j];
        }
    }
#pragma unroll
    for (int i = 0; i < 8; i++) {
        int gm = m0 + tm * 8 + i;
#pragma unroll
        for (int j = 0; j < 4; j++) {
            int gn = n0 + tn * 4 + j;
            if (gn < N) C[(long)gm * ldc + gn] = acc[i][j];
        }
    }
}

// ===== prep kernels =====
__global__ __launch_bounds__(256) void prep_wqt(const float* __restrict__ Wq_in,
                                                float* __restrict__ WqT)
{
    int idx = blockIdx.x * 256 + threadIdx.x;
    if (idx >= HH * DK * BS) return;
    int h = idx / (DK * BS), r = idx - h * DK * BS, d = r / BS, w = r - d * BS;
    WqT[idx] = Wq_in[w * (HH * DK) + h * DK + d];
}

// W_hh[n][d][g*100+w] -> Whh4[n][d][w][4]
__global__ __launch_bounds__(256) void prep_whh4(const float* __restrict__ W_hh,
                                                 float* __restrict__ Whh4)
{
    int idx = blockIdx.x * 256 + threadIdx.x;
    if (idx >= NBK * BS * G3) return;
    int n = idx / (BS * G3), r = idx - n * (BS * G3);
    int d = r / G3, e = r - d * G3;
    int g = e / BS, w = e - g * BS;
    Whh4[(((long)n * BS + d) * BS + w) * 4 + g] = W_hh[idx];
}

__global__ __launch_bounds__(256) void bias_k(const float* __restrict__ enc_b,
                                              const float* __restrict__ Wk,
                                              float* __restrict__ kbf)
{
    int j = threadIdx.x;
    if (j >= HH * DK) return;
    float acc = 0.f;
    for (int d = 0; d < NINP; d++) acc += enc_b[d] * Wk[d * (HH * DK) + j];
    kbf[j] = acc;
}

__global__ __launch_bounds__(256) void bias_c_kernel(const float* __restrict__ enc_b,
                                                     const float* __restrict__ Wv,
                                                     const float* __restrict__ kbf,
                                                     const float* __restrict__ WqT,
                                                     float* __restrict__ bias_c)
{
    int j = blockIdx.x * 256 + threadIdx.x;
    if (j >= CNP) return;
    float acc = 0.f;
    if (j < VN) {
        for (int d = 0; d < NINP; d++) acc += enc_b[d] * Wv[d * (HH * DV) + j];
    } else if (j < CN) {
        int r = j - VN;
        int h = r / BS, w = r - h * BS;
        for (int d = 0; d < DK; d++)
            acc += kbf[h * DK + d] * WqT[(h * DK + d) * BS + w];
    }
    bias_c[j] = acc;
}

__global__ __launch_bounds__(256) void cvt_dec(const float* __restrict__ dec_W,
                                               unsigned short* __restrict__ dst)
{
    int idx = blockIdx.x * 256 + threadIdx.x;
    if (idx >= NTOK * DECKP) return;
    int n = idx / DECKP, k = idx - n * DECKP;
    dst[idx] = f2b(k < NHID ? dec_W[k * NTOK + n] : 0.f);
}

__global__ __launch_bounds__(256) void cvt_split_ew(const float* __restrict__ EWfull,
                                                    unsigned short* __restrict__ dst)
{
    int idx = blockIdx.x * 256 + threadIdx.x;
    if (idx >= CNP * NTOK) return;
    int n = idx / NTOK, k = idx - n * NTOK;
    float x = (n < CN) ? EWfull[(long)k * CNP + n] : 0.f;
    unsigned short hi, mid, lo;
    split3(x, hi, mid, lo);
    long base = (long)n * (3 * KV0) + k;
    dst[base] = hi;
    dst[base + KV0] = mid;
    dst[base + 2 * KV0] = lo;
}

// W_ih -> B_U2: [4][1920][3*128]; col j = n*300 + e
__global__ __launch_bounds__(256) void cvt_split_bu2(const float* __restrict__ W_ih,
                                                     unsigned short* __restrict__ dst)
{
    int idx = blockIdx.x * 256 + threadIdx.x;
    if (idx >= HH * UN2P * UK0) return;
    int h = idx / (UN2P * UK0), r = idx - h * (UN2P * UK0);
    int j = r / UK0, kk = r - j * UK0;
    float x = 0.f;
    if (kk < DV && j < UN2) {
        int n = j / G3, e = j - n * G3;
        x = W_ih[((long)n * ATT + h * DV + kk) * G3 + e];
    }
    unsigned short hi, mid, lo;
    split3(x, hi, mid, lo);
    long base = ((long)h * UN2P + j) * (3 * UK0) + kk;
    dst[base] = hi;
    dst[base + UK0] = mid;
    dst[base + 2 * UK0] = lo;
}

// vectorized: f32x4 read, short4 writes per segment
__global__ __launch_bounds__(256) void cvt_split_in(const float* __restrict__ src,
                                                    unsigned short* __restrict__ dst, long rows)
{
    long total = rows * (NTOK / 4);
    long i = (long)blockIdx.x * 256 + threadIdx.x;
    long stride = (long)gridDim.x * 256;
    for (; i < total; i += stride) {
        long row = i / (NTOK / 4);
        int k4 = (int)(i - row * (NTOK / 4)) * 4;
        f32x4 x = *(const f32x4*)&src[row * NTOK + k4];
        short4v hi, mid, lo;
#pragma unroll
        for (int j = 0; j < 4; j++) {
            unsigned short h, m, l;
            split3(x[j], h, m, l);
            hi[j] = (short)h; mid[j] = (short)m; lo[j] = (short)l;
        }
        long base = row * (3 * KV0) + k4;
        *(short4v*)&dst[base] = hi;
        *(short4v*)&dst[base + KV0] = mid;
        *(short4v*)&dst[base + 2 * KV0] = lo;
    }
}

// ===== step kernel (R14-proven optimum): SW=2, 1024 threads, grid 256 =====
__global__ __launch_bounds__(1024) void step_fused(
    const float* __restrict__ h_prev,       // [512,600]
    const float* __restrict__ masks_t,      // [512]
    const float* __restrict__ Kbuf,         // [MU,400]
    const float* __restrict__ U,            // [4,MU,1800]
    const float* __restrict__ b_ih, const float* __restrict__ b_hh,
    const float* __restrict__ Whh4,         // [6][100][100][4]
    const float* __restrict__ Wq_c, const float* __restrict__ Wk_c,
    const float* __restrict__ Wv_c, const float* __restrict__ Wo_c,
    float* __restrict__ h_out,              // [512,600]
    unsigned short* __restrict__ A_dec,     // [MU,640] bf16
    int s_step, int MU)
{
    const int b0 = blockIdx.x * SW, tid = threadIdx.x;
    __shared__ __align__(16) float hbT[NHID][SW];
    __shared__ __align__(16) float hnT[NHID][SW];
    __shared__ __align__(16) float kp[SW][KAPN];
    __shared__ __align__(16) float qcb[SW][768], kcb[SW][768], vcb[SW][768];
    __shared__ __align__(16) float coT[NBK * 128][SW];
    __shared__ float part[SW * 96];
    __shared__ float att[SW][24], mk[SW][NBK];
    __shared__ float lg[SW][144];

    const long rowd0 = (long)s_step * BATCH + b0;
    const int n2 = (tid < 600) ? tid / 100 : 0;
    const int w2 = (tid < 600) ? tid - n2 * 100 : 0;

    // ---- EARLY ISSUE: U gather (consumed in P2, ~5 barriers later) ----
    float uraw[HH][3][SW];
    if (tid < 600) {
#pragma unroll
        for (int h = 0; h < HH; h++) {
            const float* Uh = U + ((long)h * MU + rowd0) * UN2 + n2 * G3;
#pragma unroll
            for (int s = 0; s < SW; s++)
#pragma unroll
                for (int g = 0; g < 3; g++)
                    uraw[h][g][s] = Uh[(long)s * UN2 + g * BS + w2];
        }
    }

    // ---- P0: load state (transposed) + kappa ----
    for (int i = tid; i < SW * NHID; i += 1024) {
        int s = i / NHID, j = i - s * NHID;
        hbT[j][s] = h_prev[(long)(b0 + s) * NHID + j] * masks_t[b0 + s];
    }
    for (int i = tid; i < SW * KAPN; i += 1024) {
        int s = i / KAPN, j = i - s * KAPN;
        kp[s][j] = Kbuf[(rowd0 + s) * KAPN + j];
    }
    __syncthreads();
    // ---- P1: input-attention logits ----
    if (tid < SW * 96) {
        int g = tid >> 2, q = tid & 3;
        int s = g / 24, r = g - s * 24;
        int n = r >> 2, h = r & 3;
        float acc = 0.f;
        int w0 = q * 25;
        for (int w = w0; w < w0 + 25; w++) acc += hbT[n * BS + w][s] * kp[s][h * BS + w];
        part[tid] = acc;
    }
    __syncthreads();
    if (tid < SW * 24) {
        int s = tid / 24, r = tid - s * 24;
        float l = part[tid * 4] + part[tid * 4 + 1] + part[tid * 4 + 2] + part[tid * 4 + 3];
        att[s][r] = sigf(l * 0.125f);        // softmax([l,0])[0] == sigmoid(l)
    }
    __syncthreads();
    if (tid < SW) {
        float a[NBK], av[NBK];
        for (int n = 0; n < NBK; n++) {
            av[n] = 0.25f * (att[tid][n * 4] + att[tid][n * 4 + 1] + att[tid][n * 4 + 2] + att[tid][n * 4 + 3]);
            a[n] = av[n];
        }
        for (int i = 0; i < 4; i++) {
            int mx = i;
            for (int j = i + 1; j < NBK; j++) if (a[j] > a[mx]) mx = j;
            float t = a[i]; a[i] = a[mx]; a[mx] = t;
        }
        float kth = a[3];
        for (int n = 0; n < NBK; n++) mk[tid][n] = (av[n] >= kth) ? 1.f : 0.f;
    }

    // ---- P2: GRU — gi (early-fetched U) + gh (f32x4 Whh4, deep unroll) ----
    if (tid < 600) {
        float gi[3][SW], gh[3][SW];
#pragma unroll
        for (int g = 0; g < 3; g++) {
            float bi = b_ih[n2 * G3 + g * BS + w2];
            float bh = b_hh[n2 * G3 + g * BS + w2];
#pragma unroll
            for (int s = 0; s < SW; s++) { gi[g][s] = bi; gh[g][s] = bh; }
        }
#pragma unroll
        for (int h = 0; h < HH; h++)
#pragma unroll
            for (int s = 0; s < SW; s++) {
                float a = att[s][n2 * 4 + h];
#pragma unroll
                for (int g = 0; g < 3; g++)
                    gi[g][s] += a * uraw[h][g][s];
            }
        const f32x4* Wn4 = ((const f32x4*)Whh4) + (long)n2 * BS * BS + w2;
#pragma unroll 10
        for (int d = 0; d < BS; d++) {
            f32x4 wv = Wn4[(long)d * BS];
            float2 hv = *(const float2*)&hbT[n2 * BS + d][0];
            gh[0][0] += wv[0] * hv.x; gh[0][1] += wv[0] * hv.y;
            gh[1][0] += wv[1] * hv.x; gh[1][1] += wv[1] * hv.y;
            gh[2][0] += wv[2] * hv.x; gh[2][1] += wv[2] * hv.y;
        }
        float2 hnv;
        {
            float rr0 = sigf(gi[0][0] + gh[0][0]);
            float zz0 = sigf(gi[1][0] + gh[1][0]);
            float ng0 = tanhf(gi[2][0] + rr0 * gh[2][0]);
            hnv.x = (1.f - zz0) * ng0 + zz0 * hbT[n2 * BS + w2][0];
            float rr1 = sigf(gi[0][1] + gh[0][1]);
            float zz1 = sigf(gi[1][1] + gh[1][1]);
            float ng1 = tanhf(gi[2][1] + rr1 * gh[2][1]);
            hnv.y = (1.f - zz1) * ng1 + zz1 * hbT[n2 * BS + w2][1];
        }
        *(float2*)&hnT[n2 * BS + w2][0] = hnv;
    }
    __syncthreads();

    // ---- P3: comm projections (direct-L2 Wq/k/v_c, deep unroll) ----
    if (tid < 768) {
        const int mat = tid >> 8, r = tid & 255, ng = r >> 7, c = r & 127;
        const float* W = (mat == 0) ? Wq_c : ((mat == 1) ? Wk_c : Wv_c);
        float acc[3][SW];
#pragma unroll
        for (int j = 0; j < 3; j++)
#pragma unroll
            for (int s = 0; s < SW; s++) acc[j][s] = 0.f;
#pragma unroll 10
        for (int d = 0; d < BS; d++) {
            float wv = W[d * 128 + c];
#pragma unroll
            for (int j = 0; j < 3; j++) {
                float2 hv = *(const float2*)&hnT[(ng * 3 + j) * BS + d][0];
                acc[j][0] += wv * hv.x;
                acc[j][1] += wv * hv.y;
            }
        }
        float (*dst)[768] = (mat == 0) ? qcb : ((mat == 1) ? kcb : vcb);
#pragma unroll
        for (int j = 0; j < 3; j++)
#pragma unroll
            for (int s = 0; s < SW; s++)
                dst[s][(ng * 3 + j) * 128 + c] = acc[j][s];
    }
    __syncthreads();

    // ---- P4: comm attention logits + softmax + co ----
    if (tid < SW * 144) {
        int s = tid / 144, r = tid - s * 144;
        int h = r / 36, r2 = r - h * 36, n = r2 / NBK, m = r2 - n * NBK;
        float sv = 0.f;
#pragma unroll
        for (int e4 = 0; e4 < 8; e4++) {
            f32x4 qv = *(const f32x4*)&qcb[s][n * 128 + h * 32 + e4 * 4];
            f32x4 kv = *(const f32x4*)&kcb[s][m * 128 + h * 32 + e4 * 4];
            sv += qv[0] * kv[0] + qv[1] * kv[1] + qv[2] * kv[2] + qv[3] * kv[3];
        }
        lg[s][r] = sv * 0.17677669529663687f;
    }
    __syncthreads();
    if (tid < SW * 24) {
        int s = tid / 24, r = tid - s * 24;
        float* row = &lg[s][r * NBK];
        float mx = row[0];
        for (int m = 1; m < NBK; m++) mx = fmaxf(mx, row[m]);
        float sv = 0.f;
        for (int m = 0; m < NBK; m++) { row[m] = expf(row[m] - mx); sv += row[m]; }
        float inv = 1.f / sv;
        for (int m = 0; m < NBK; m++) row[m] *= inv;
    }
    __syncthreads();
    for (int idx = tid; idx < SW * 768; idx += 1024) {
        int s = idx / 768, r = idx - s * 768;
        int n = r >> 7, d = r & 127, h = d >> 5;
        float a = 0.f;
#pragma unroll
        for (int m = 0; m < NBK; m++) a += lg[s][h * 36 + n * NBK + m] * vcb[s][m * 128 + d];
        coT[r][s] = a;
    }
    __syncthreads();

    // ---- P5: co @ Wo_c (deep unroll) + masked select ----
    if (tid < 600) {
        float a0 = 0.f, a1 = 0.f;
#pragma unroll 8
        for (int d = 0; d < 128; d++) {
            float wv = Wo_c[d * BS + w2];
            float2 cv = *(const float2*)&coT[n2 * 128 + d][0];
            a0 += wv * cv.x;
            a1 += wv * cv.y;
        }
        float2 res;
        float hc0 = hnT[n2 * BS + w2][0] + a0;
        float hc1 = hnT[n2 * BS + w2][1] + a1;
        res.x = (mk[0][n2] > 0.5f) ? hc0 : hbT[n2 * BS + w2][0];
        res.y = (mk[1][n2] > 0.5f) ? hc1 : hbT[n2 * BS + w2][1];
        *(float2*)&hbT[n2 * BS + w2][0] = res;
    }
    __syncthreads();
    // ---- P6: coalesced global writes ----
    for (int i = tid; i < SW * NHID; i += 1024) {
        int s = i / NHID, j = i - s * NHID;
        h_out[(long)(b0 + s) * NHID + j] = hbT[j][s];
    }
    for (int i = tid; i < SW * DECKP; i += 1024) {
        int s = i / DECKP, col = i - s * DECKP;
        A_dec[(rowd0 + s) * DECKP + col] = f2b(col < NHID ? hbT[col][s] : 0.f);
    }
}

// ===== host launch =====
extern "C" void kernel_launch(void* const* d_in, const int* in_sizes, int n_in,
                              void* d_out, int out_size, void* d_ws, size_t ws_size,
                              hipStream_t stream)
{
    const float* input = (const float*)d_in[0];
    const float* h0    = (const float*)d_in[1];
    const float* masks = (const float*)d_in[2];
    const float* enc_W = (const float*)d_in[3];
    const float* enc_b = (const float*)d_in[4];
    const float* Wq_in = (const float*)d_in[5];
    const float* Wk_in = (const float*)d_in[6];
    const float* Wv_in = (const float*)d_in[7];
    const float* W_ih  = (const float*)d_in[8];
    const float* W_hh  = (const float*)d_in[9];
    const float* b_ih  = (const float*)d_in[10];
    const float* b_hh  = (const float*)d_in[11];
    const float* Wq_c  = (const float*)d_in[12];
    const float* Wk_c  = (const float*)d_in[13];
    const float* Wv_c  = (const float*)d_in[14];
    const float* Wo_c  = (const float*)d_in[15];
    const float* dec_W = (const float*)d_in[16];
    const float* dec_b = (const float*)d_in[17];
    float* out = (float*)d_out;

    const size_t AL = 256;
    auto pad = [&](size_t x) { return (x + AL - 1) & ~(AL - 1); };
    size_t fixedB = pad((size_t)NTOK * CNP * 4)
                  + pad((size_t)NTOK * 256 * 4)
                  + pad((size_t)HH * DK * BS * 4)
                  + pad((size_t)256 * 4)
                  + pad((size_t)CNP * 4)
                  + pad((size_t)NBK * BS * BS * 4 * 4)     // Whh4
                  + pad((size_t)CNP * 3 * KV0 * 2)
                  + pad((size_t)HH * UN2P * 3 * UK0 * 2)
                  + pad((size_t)NTOK * DECKP * 2)
                  + 2 * pad((size_t)BATCH * NHID * 4);
    auto perC = [&](int C) {
        size_t MU = (size_t)C * BATCH;
        return pad(MU * 3 * KV0 * 2)
             + pad(MU * KAPN * 4)
             + pad((size_t)HH * MU * 3 * UK0 * 2)
             + pad((size_t)HH * MU * UN2 * 4)
             + pad(MU * DECKP * 2);
    };
    int C = 8;
    while (C > 1 && fixedB + perC(C) > ws_size) C >>= 1;
    const int MU = C * BATCH;
    const int NCH = T_STEPS / C;

    char* p = (char*)d_ws;
    auto alloc = [&](size_t bytes) { char* r = p; p += pad(bytes); return r; };
    float*          EWfull = (float*)alloc((size_t)NTOK * CNP * 4);
    float*          EWk    = (float*)alloc((size_t)NTOK * 256 * 4);
    float*          WqT    = (float*)alloc((size_t)HH * DK * BS * 4);
    float*          kbf    = (float*)alloc((size_t)256 * 4);
    float*          bias_c = (float*)alloc((size_t)CNP * 4);
    float*          Whh4   = (float*)alloc((size_t)NBK * BS * BS * 4 * 4);
    unsigned short* B_vkap = (unsigned short*)alloc((size_t)CNP * 3 * KV0 * 2);
    unsigned short* B_U    = (unsigned short*)alloc((size_t)HH * UN2P * 3 * UK0 * 2);
    unsigned short* B_dec  = (unsigned short*)alloc((size_t)NTOK * DECKP * 2);
    float*          hA     = (float*)alloc((size_t)BATCH * NHID * 4);
    float*          hB     = (float*)alloc((size_t)BATCH * NHID * 4);
    unsigned short* A_in   = (unsigned short*)alloc((size_t)MU * 3 * KV0 * 2);
    float*          Kbuf   = (float*)alloc((size_t)MU * KAPN * 4);
    unsigned short* A_U    = (unsigned short*)alloc((size_t)HH * MU * 3 * UK0 * 2);
    float*          Ubuf   = (float*)alloc((size_t)HH * MU * UN2 * 4);
    unsigned short* A_dec  = (unsigned short*)alloc((size_t)MU * DECKP * 2);

    dim3 blk(256);
    ZOff z0 = {1, 0, 0};

    // ---- setup ----
    sgemm<<<dim3(6, 4, 1), blk, 0, stream>>>(
        enc_W, z0, NINP, Wv_in, z0, HH * DV, EWfull, z0, CNP, NTOK, VN, NINP);
    sgemm<<<dim3(4, 4, 1), blk, 0, stream>>>(
        enc_W, z0, NINP, Wk_in, z0, HH * DK, EWk, z0, 256, NTOK, HH * DK, NINP);
    prep_wqt<<<dim3((HH * DK * BS + 255) / 256), blk, 0, stream>>>(Wq_in, WqT);
    prep_whh4<<<dim3((NBK * BS * G3 + 255) / 256), blk, 0, stream>>>(W_hh, Whh4);
    sgemm<<<dim3(2, 4, HH), blk, 0, stream>>>(
        EWk, ZOff{1, DK, 0}, 256, WqT, ZOff{1, (long)DK * BS, 0}, BS,
        EWfull + VN, ZOff{1, BS, 0}, CNP, NTOK, BS, DK);
    bias_k<<<dim3(1), blk, 0, stream>>>(enc_b, Wk_in, kbf);
    bias_c_kernel<<<dim3(3), blk, 0, stream>>>(enc_b, Wv_in, kbf, WqT, bias_c);
    cvt_split_ew<<<dim3((CNP * NTOK + 255) / 256), blk, 0, stream>>>(EWfull, B_vkap);
    cvt_split_bu2<<<dim3((HH * UN2P * UK0 + 255) / 256), blk, 0, stream>>>(W_ih, B_U);
    cvt_dec<<<dim3((NTOK * DECKP + 255) / 256), blk, 0, stream>>>(dec_W, B_dec);

    const float* hp = h0;
    float* hbufs[2] = { hA, hB };
    int t = 0;
    for (int c = 0; c < NCH; c++) {
        cvt_split_in<<<dim3(2048), blk, 0, stream>>>(
            input + (size_t)c * MU * NTOK, A_in, MU);
        gemm6_kv64<<<dim3(CNP / 128, MU / 64, 1), blk, 0, stream>>>(
            A_in, B_vkap, A_U, Kbuf, bias_c, KV0, MU);
        gemm6<<<dim3(UN2P / 128, MU / 128, HH), blk, 0, stream>>>(
            A_U, (long)MU * 3 * UK0, 1, B_U, (long)UN2P * 3 * UK0,
            Ubuf, (long)MU * UN2, UN2, UN2, nullptr, UK0);
        for (int s = 0; s < C; s++, t++) {
            float* hout = hbufs[t & 1];
            step_fused<<<dim3(BATCH / SW), dim3(1024), 0, stream>>>(
                hp, masks + (size_t)t * BATCH, Kbuf, Ubuf, b_ih, b_hh, Whh4,
                Wq_c, Wk_c, Wv_c, Wo_c, hout, A_dec, s, MU);
            hp = hout;
        }
        gemm_mfma64<<<dim3(NTOK / 128, MU / 64, 1), blk, 0, stream>>>(
            A_dec, B_dec, out + (size_t)c * MU * NTOK, NTOK, dec_b, DECKP);
    }
}

// Round 17
// 5419.085 us; speedup vs baseline: 1.3835x; 1.1069x over previous
//
#include <hip/hip_runtime.h>
#include <math.h>

#define T_STEPS 128
#define BATCH   512
#define NTOK    512
#define NINP    512
#define NHID    600
#define NBK     6
#define BS      100
#define HH      4
#define DK      64
#define DV      85
#define ATT     340
#define H2      4
#define DK2     32
#define DV2     32
#define G3      300
#define VN      340
#define KAPN    400
#define CN      740
#define CNP     768
#define UN2     1800     // merged U cols per head (6 blocks x 300)
#define UN2P    1920     // padded to 15*128
#define UK0     128
#define KV0     512
#define DECKP   640
#define SW      2        // samples per step-block -> grid 256 = all CUs (measured optimum R14)

typedef __attribute__((ext_vector_type(8))) short short8;
typedef __attribute__((ext_vector_type(4))) short short4v;
typedef __attribute__((ext_vector_type(4))) float f32x4;

typedef __attribute__((address_space(1))) const unsigned int* g1ptr;
typedef __attribute__((address_space(3))) unsigned int* l3ptr;

__device__ __forceinline__ float sigf(float x) { return 1.f / (1.f + expf(-x)); }
__device__ __forceinline__ unsigned short f2b(float f) {
    unsigned u = __float_as_uint(f);
    unsigned r = (u + 0x7fffu + ((u >> 16) & 1u)) >> 16;
    return (unsigned short)r;
}
__device__ __forceinline__ float b2f(unsigned short u) {
    return __uint_as_float(((unsigned)u) << 16);
}
__device__ __forceinline__ void split3(float x, unsigned short& hi,
                                       unsigned short& mid, unsigned short& lo) {
    hi = f2b(x);
    float r1 = x - b2f(hi);
    mid = f2b(r1);
    lo = f2b(r1 - b2f(mid));
}

struct ZOff { int div; long s1; long s2; };
__device__ __forceinline__ long zoff(ZOff z, int bz) {
    return (long)(bz / z.div) * z.s1 + (long)(bz % z.div) * z.s2;
}

// Stage a 128x64-short tile into LDS via async global_load_lds (16B/lane).
__device__ __forceinline__ void stage_tile(const unsigned short* __restrict__ gbase,
                                           long rowStride, int m0, int k0,
                                           unsigned short* lds, int tid)
{
    const int w = tid >> 6;
#pragma unroll
    for (int q = 0; q < 4; q++) {
        int idx = (q << 8) + tid;
        int r = idx >> 3, ce = (idx & 7) << 3;
        const unsigned short* g = gbase + (long)(m0 + r) * rowStride + k0 + ce;
        unsigned short* l = lds + q * 2048 + w * 512;   // wave-uniform base
        __builtin_amdgcn_global_load_lds((g1ptr)(const void*)g, (l3ptr)(void*)l, 16, 0, 0);
    }
}
// 64-row variant (2 rounds)
__device__ __forceinline__ void stage_tile64(const unsigned short* __restrict__ gbase,
                                             long rowStride, int m0, int k0,
                                             unsigned short* lds, int tid)
{
    const int w = tid >> 6;
#pragma unroll
    for (int q = 0; q < 2; q++) {
        int idx = (q << 8) + tid;
        int r = idx >> 3, ce = (idx & 7) << 3;
        const unsigned short* g = gbase + (long)(m0 + r) * rowStride + k0 + ce;
        unsigned short* l = lds + q * 2048 + w * 512;
        __builtin_amdgcn_global_load_lds((g1ptr)(const void*)g, (l3ptr)(void*)l, 16, 0, 0);
    }
}

// ===== U GEMM: 64x128 tile, all-segment staging per k0 (96 MFMA / barrier-pair) =====
// A bf16 3-seg [rows][3*K0] (z-batched by head), B^T 3-seg [1920][3*K0]. K0=128.
__global__ __launch_bounds__(256) void gemm6_useg(
    const unsigned short* __restrict__ A, long aZ,
    const unsigned short* __restrict__ B, long bZ,
    float* __restrict__ C, long cZ, int ldc, int Nreal, int K0)
{
    const int bz = blockIdx.z;
    A += (long)bz * aZ;
    B += (long)bz * bZ;
    C += (long)bz * cZ;
    const int LDA = 3 * K0;
    const int m0 = blockIdx.y * 64, n0 = blockIdx.x * 128;
    __shared__ __align__(16) unsigned short As3[3][64 * 64];
    __shared__ __align__(16) unsigned short Bs3[3][128 * 64];
    const int tid = threadIdx.x;
    const int lane = tid & 63;
    const int w = tid >> 6;

    f32x4 acc[4][2];
#pragma unroll
    for (int m = 0; m < 4; m++)
#pragma unroll
        for (int n = 0; n < 2; n++)
#pragma unroll
            for (int v = 0; v < 4; v++) acc[m][n][v] = 0.f;

    const int segA[6] = {0, 0, 1, 0, 2, 1};
    const int segB[6] = {0, 1, 0, 2, 0, 1};
    for (int k0 = 0; k0 < K0; k0 += 64) {
        __syncthreads();                        // prior MFMAs done reading LDS
#pragma unroll
        for (int s = 0; s < 3; s++) stage_tile64(A + s * K0, LDA, m0, k0, As3[s], tid);
#pragma unroll
        for (int s = 0; s < 3; s++) stage_tile(B + s * K0, LDA, n0, k0, Bs3[s], tid);
        __syncthreads();                        // vmcnt drained -> data in LDS
#pragma unroll
        for (int p = 0; p < 6; p++) {
            const unsigned short* Asl = As3[segA[p]];
            const unsigned short* Bsl = Bs3[segB[p]];
#pragma unroll
            for (int kk = 0; kk < 2; kk++) {
                short8 af[4], bfr[2];
#pragma unroll
                for (int m = 0; m < 4; m++)
                    af[m] = *(const short8*)&Asl[(m * 16 + (lane & 15)) * 64 + kk * 32 + (lane >> 4) * 8];
#pragma unroll
                for (int n = 0; n < 2; n++)
                    bfr[n] = *(const short8*)&Bsl[(w * 32 + n * 16 + (lane & 15)) * 64 + kk * 32 + (lane >> 4) * 8];
#pragma unroll
                for (int m = 0; m < 4; m++)
#pragma unroll
                    for (int n = 0; n < 2; n++)
                        acc[m][n] = __builtin_amdgcn_mfma_f32_16x16x32_bf16(af[m], bfr[n], acc[m][n], 0, 0, 0);
            }
        }
    }
#pragma unroll
    for (int m = 0; m < 4; m++) {
        int rbase = m0 + m * 16 + (lane >> 4) * 4;
#pragma unroll
        for (int n = 0; n < 2; n++) {
            int col = n0 + w * 32 + n * 16 + (lane & 15);
            if (col < Nreal) {
#pragma unroll
                for (int v = 0; v < 4; v++)
                    C[(long)(rbase + v) * ldc + col] = acc[m][n][v];
            }
        }
    }
}

// ===== kv GEMM: A = fp32 input with in-reg split3 (no A_in buffer); 64x128 tile =====
__global__ __launch_bounds__(256) void gemm6_kvseg(
    const float* __restrict__ X,            // [MU][512] fp32 input chunk
    const unsigned short* __restrict__ B,   // [768][3*512] bf16 3-seg
    unsigned short* __restrict__ A_U,       // [4][MU][3*UK0]
    float* __restrict__ Kbuf,               // [MU][400]
    const float* __restrict__ bias, int MU)
{
    const int m0 = blockIdx.y * 64, n0 = blockIdx.x * 128;
    __shared__ __align__(16) unsigned short As3[3][64 * 64];
    __shared__ __align__(16) unsigned short Bs3[3][128 * 64];
    const int tid = threadIdx.x;
    const int lane = tid & 63;
    const int w = tid >> 6;

    f32x4 acc[4][2];
#pragma unroll
    for (int m = 0; m < 4; m++)
#pragma unroll
        for (int n = 0; n < 2; n++)
#pragma unroll
            for (int v = 0; v < 4; v++) acc[m][n][v] = 0.f;

    const int segA[6] = {0, 0, 1, 0, 2, 1};
    const int segB[6] = {0, 1, 0, 2, 0, 1};
    for (int k0 = 0; k0 < KV0; k0 += 64) {
        // reg-load A fp32 tile 64x64 (4 rounds of f32x4)
        f32x4 xv[4];
#pragma unroll
        for (int q = 0; q < 4; q++) {
            int idx = (q << 8) + tid;
            int r = idx >> 4, c4 = (idx & 15) << 2;
            xv[q] = *(const f32x4*)&X[(long)(m0 + r) * KV0 + k0 + c4];
        }
        __syncthreads();                        // prior MFMAs done reading LDS
        // B: async gload_lds for all 3 segments
#pragma unroll
        for (int s = 0; s < 3; s++) stage_tile(B + s * KV0, 3 * KV0, n0, k0, Bs3[s], tid);
        // A: split in regs, ds_write 3 segment tiles
#pragma unroll
        for (int q = 0; q < 4; q++) {
            int idx = (q << 8) + tid;
            int r = idx >> 4, c4 = (idx & 15) << 2;
            short4v hs, ms, ls;
#pragma unroll
            for (int j = 0; j < 4; j++) {
                unsigned short h, m, l;
                split3(xv[q][j], h, m, l);
                hs[j] = (short)h; ms[j] = (short)m; ls[j] = (short)l;
            }
            *(short4v*)&As3[0][r * 64 + c4] = hs;
            *(short4v*)&As3[1][r * 64 + c4] = ms;
            *(short4v*)&As3[2][r * 64 + c4] = ls;
        }
        __syncthreads();                        // vmcnt + lgkmcnt drained
#pragma unroll
        for (int p = 0; p < 6; p++) {
            const unsigned short* Asl = As3[segA[p]];
            const unsigned short* Bsl = Bs3[segB[p]];
#pragma unroll
            for (int kk = 0; kk < 2; kk++) {
                short8 af[4], bfr[2];
#pragma unroll
                for (int m = 0; m < 4; m++)
                    af[m] = *(const short8*)&Asl[(m * 16 + (lane & 15)) * 64 + kk * 32 + (lane >> 4) * 8];
#pragma unroll
                for (int n = 0; n < 2; n++)
                    bfr[n] = *(const short8*)&Bsl[(w * 32 + n * 16 + (lane & 15)) * 64 + kk * 32 + (lane >> 4) * 8];
#pragma unroll
                for (int m = 0; m < 4; m++)
#pragma unroll
                    for (int n = 0; n < 2; n++)
                        acc[m][n] = __builtin_amdgcn_mfma_f32_16x16x32_bf16(af[m], bfr[n], acc[m][n], 0, 0, 0);
            }
        }
    }
#pragma unroll
    for (int m = 0; m < 4; m++) {
        int rbase = m0 + m * 16 + (lane >> 4) * 4;
#pragma unroll
        for (int n = 0; n < 2; n++) {
            int col = n0 + w * 32 + n * 16 + (lane & 15);
            if (col < CN) {
                float bv = bias[col];
                if (col < VN) {
                    int h = col / DV, kk2 = col - h * DV;
#pragma unroll
                    for (int v = 0; v < 4; v++) {
                        float val = acc[m][n][v] + bv;
                        unsigned short hi, mid, lo;
                        split3(val, hi, mid, lo);
                        long base = ((long)h * MU + (rbase + v)) * (3 * UK0) + kk2;
                        A_U[base] = hi;
                        A_U[base + UK0] = mid;
                        A_U[base + 2 * UK0] = lo;
                    }
                } else {
                    int kc = col - VN;
#pragma unroll
                    for (int v = 0; v < 4; v++)
                        Kbuf[(long)(rbase + v) * KAPN + kc] = acc[m][n][v] + bv;
                }
            }
        }
    }
}

// ===== plain bf16 MFMA GEMM, 64x128 tile (decoder) =====
__global__ __launch_bounds__(256) void gemm_mfma64(
    const unsigned short* __restrict__ A,
    const unsigned short* __restrict__ B,
    float* __restrict__ C, int ldc,
    const float* __restrict__ bias, int Kp)
{
    const int m0 = blockIdx.y * 64, n0 = blockIdx.x * 128;
    __shared__ __align__(16) unsigned short As[64 * 64];
    __shared__ __align__(16) unsigned short Bs[128 * 64];
    const int tid = threadIdx.x;
    const int lane = tid & 63;
    const int w = tid >> 6;

    f32x4 acc[4][2];
#pragma unroll
    for (int m = 0; m < 4; m++)
#pragma unroll
        for (int n = 0; n < 2; n++)
#pragma unroll
            for (int v = 0; v < 4; v++) acc[m][n][v] = 0.f;

    for (int k0 = 0; k0 < Kp; k0 += 64) {
        __syncthreads();
        stage_tile64(A, Kp, m0, k0, As, tid);
        stage_tile(B, Kp, n0, k0, Bs, tid);
        __syncthreads();
#pragma unroll
        for (int kk = 0; kk < 2; kk++) {
            short8 af[4], bfr[2];
#pragma unroll
            for (int m = 0; m < 4; m++)
                af[m] = *(const short8*)&As[(m * 16 + (lane & 15)) * 64 + kk * 32 + (lane >> 4) * 8];
#pragma unroll
            for (int n = 0; n < 2; n++)
                bfr[n] = *(const short8*)&Bs[(w * 32 + n * 16 + (lane & 15)) * 64 + kk * 32 + (lane >> 4) * 8];
#pragma unroll
            for (int m = 0; m < 4; m++)
#pragma unroll
                for (int n = 0; n < 2; n++)
                    acc[m][n] = __builtin_amdgcn_mfma_f32_16x16x32_bf16(af[m], bfr[n], acc[m][n], 0, 0, 0);
        }
    }
#pragma unroll
    for (int m = 0; m < 4; m++) {
        int rbase = m0 + m * 16 + (lane >> 4) * 4;
#pragma unroll
        for (int n = 0; n < 2; n++) {
            int col = n0 + w * 32 + n * 16 + (lane & 15);
            float bv = bias ? bias[col] : 0.f;
#pragma unroll
            for (int v = 0; v < 4; v++)
                C[(long)(rbase + v) * ldc + col] = acc[m][n][v] + bv;
        }
    }
}

// ===== fp32 SGEMM (setup-only small jobs) =====
__global__ __launch_bounds__(256) void sgemm(
    const float* __restrict__ A, ZOff za, int lda,
    const float* __restrict__ B, ZOff zb, int ldb,
    float* __restrict__ C, ZOff zc, int ldc,
    int M, int N, int K)
{
    const int bz = blockIdx.z;
    A += zoff(za, bz);
    B += zoff(zb, bz);
    C += zoff(zc, bz);
    const int m0 = blockIdx.y * 128, n0 = blockIdx.x * 64;
    __shared__ float As[16][132];
    __shared__ float Bs[16][68];
    const int tid = threadIdx.x;
    const int tm = tid >> 4, tn = tid & 15;
    const int ar = tid >> 1, ak = (tid & 1) * 8;
    const int bk = tid >> 4, bn = (tid & 15) * 4;

    float acc[8][4];
#pragma unroll
    for (int i = 0; i < 8; i++)
#pragma unroll
        for (int j = 0; j < 4; j++) acc[i][j] = 0.f;

    for (int k0 = 0; k0 < K; k0 += 16) {
        float av[8], bv[4];
#pragma unroll
        for (int j = 0; j < 8; j++) {
            int gk = k0 + ak + j;
            av[j] = (gk < K) ? A[(long)(m0 + ar) * lda + gk] : 0.f;
        }
#pragma unroll
        for (int j = 0; j < 4; j++) {
            int gk = k0 + bk, gn = n0 + bn + j;
            bv[j] = (gk < K && gn < N) ? B[(long)gk * ldb + gn] : 0.f;
        }
        __syncthreads();
#pragma unroll
        for (int j = 0; j < 8; j++) As[ak + j][ar] = av[j];
#pragma unroll
        for (int j = 0; j < 4; j++) Bs[bk][bn + j] = bv[j];
        __syncthreads();
#pragma unroll
        for (int kk = 0; kk < 16; kk++) {
            float a[8], b[4];
#pragma unroll
            for (int i = 0; i < 8; i++) a[i] = As[kk][tm * 8 + i];
#pragma unroll
            for (int j = 0; j < 4; j++) b[j] = Bs[kk][tn * 4 + j];
#pragma unroll
            for (int i = 0; i < 8; i++)
#pragma unroll
                for (int j = 0; j < 4; j++)
                    acc[i][j] += a[i] * b[j];
        }
    }
#pragma unroll
    for (int i = 0; i < 8; i++) {
        int gm = m0 + tm * 8 + i;
#pragma unroll
        for (int j = 0; j < 4; j++) {
            int gn = n0 + tn * 4 + j;
            if (gn < N) C[(long)gm * ldc + gn] = acc[i][j];
        }
    }
}

// ===== prep kernels =====
__global__ __launch_bounds__(256) void prep_wqt(const float* __restrict__ Wq_in,
                                                float* __restrict__ WqT)
{
    int idx = blockIdx.x * 256 + threadIdx.x;
    if (idx >= HH * DK * BS) return;
    int h = idx / (DK * BS), r = idx - h * DK * BS, d = r / BS, w = r - d * BS;
    WqT[idx] = Wq_in[w * (HH * DK) + h * DK + d];
}

// W_hh[n][d][g*100+w] -> Whh4[n][d][w][4]
__global__ __launch_bounds__(256) void prep_whh4(const float* __restrict__ W_hh,
                                                 float* __restrict__ Whh4)
{
    int idx = blockIdx.x * 256 + threadIdx.x;
    if (idx >= NBK * BS * G3) return;
    int n = idx / (BS * G3), r = idx - n * (BS * G3);
    int d = r / G3, e = r - d * G3;
    int g = e / BS, w = e - g * BS;
    Whh4[(((long)n * BS + d) * BS + w) * 4 + g] = W_hh[idx];
}

__global__ __launch_bounds__(256) void bias_k(const float* __restrict__ enc_b,
                                              const float* __restrict__ Wk,
                                              float* __restrict__ kbf)
{
    int j = threadIdx.x;
    if (j >= HH * DK) return;
    float acc = 0.f;
    for (int d = 0; d < NINP; d++) acc += enc_b[d] * Wk[d * (HH * DK) + j];
    kbf[j] = acc;
}

__global__ __launch_bounds__(256) void bias_c_kernel(const float* __restrict__ enc_b,
                                                     const float* __restrict__ Wv,
                                                     const float* __restrict__ kbf,
                                                     const float* __restrict__ WqT,
                                                     float* __restrict__ bias_c)
{
    int j = blockIdx.x * 256 + threadIdx.x;
    if (j >= CNP) return;
    float acc = 0.f;
    if (j < VN) {
        for (int d = 0; d < NINP; d++) acc += enc_b[d] * Wv[d * (HH * DV) + j];
    } else if (j < CN) {
        int r = j - VN;
        int h = r / BS, w = r - h * BS;
        for (int d = 0; d < DK; d++)
            acc += kbf[h * DK + d] * WqT[(h * DK + d) * BS + w];
    }
    bias_c[j] = acc;
}

__global__ __launch_bounds__(256) void cvt_dec(const float* __restrict__ dec_W,
                                               unsigned short* __restrict__ dst)
{
    int idx = blockIdx.x * 256 + threadIdx.x;
    if (idx >= NTOK * DECKP) return;
    int n = idx / DECKP, k = idx - n * DECKP;
    dst[idx] = f2b(k < NHID ? dec_W[k * NTOK + n] : 0.f);
}

__global__ __launch_bounds__(256) void cvt_split_ew(const float* __restrict__ EWfull,
                                                    unsigned short* __restrict__ dst)
{
    int idx = blockIdx.x * 256 + threadIdx.x;
    if (idx >= CNP * NTOK) return;
    int n = idx / NTOK, k = idx - n * NTOK;
    float x = (n < CN) ? EWfull[(long)k * CNP + n] : 0.f;
    unsigned short hi, mid, lo;
    split3(x, hi, mid, lo);
    long base = (long)n * (3 * KV0) + k;
    dst[base] = hi;
    dst[base + KV0] = mid;
    dst[base + 2 * KV0] = lo;
}

// W_ih -> B_U2: [4][1920][3*128]; col j = n*300 + e
__global__ __launch_bounds__(256) void cvt_split_bu2(const float* __restrict__ W_ih,
                                                     unsigned short* __restrict__ dst)
{
    int idx = blockIdx.x * 256 + threadIdx.x;
    if (idx >= HH * UN2P * UK0) return;
    int h = idx / (UN2P * UK0), r = idx - h * (UN2P * UK0);
    int j = r / UK0, kk = r - j * UK0;
    float x = 0.f;
    if (kk < DV && j < UN2) {
        int n = j / G3, e = j - n * G3;
        x = W_ih[((long)n * ATT + h * DV + kk) * G3 + e];
    }
    unsigned short hi, mid, lo;
    split3(x, hi, mid, lo);
    long base = ((long)h * UN2P + j) * (3 * UK0) + kk;
    dst[base] = hi;
    dst[base + UK0] = mid;
    dst[base + 2 * UK0] = lo;
}

// ===== step kernel (R14-proven optimum): SW=2, 1024 threads, grid 256 =====
__global__ __launch_bounds__(1024) void step_fused(
    const float* __restrict__ h_prev,       // [512,600]
    const float* __restrict__ masks_t,      // [512]
    const float* __restrict__ Kbuf,         // [MU,400]
    const float* __restrict__ U,            // [4,MU,1800]
    const float* __restrict__ b_ih, const float* __restrict__ b_hh,
    const float* __restrict__ Whh4,         // [6][100][100][4]
    const float* __restrict__ Wq_c, const float* __restrict__ Wk_c,
    const float* __restrict__ Wv_c, const float* __restrict__ Wo_c,
    float* __restrict__ h_out,              // [512,600]
    unsigned short* __restrict__ A_dec,     // [MU,640] bf16
    int s_step, int MU)
{
    const int b0 = blockIdx.x * SW, tid = threadIdx.x;
    __shared__ __align__(16) float hbT[NHID][SW];
    __shared__ __align__(16) float hnT[NHID][SW];
    __shared__ __align__(16) float kp[SW][KAPN];
    __shared__ __align__(16) float qcb[SW][768], kcb[SW][768], vcb[SW][768];
    __shared__ __align__(16) float coT[NBK * 128][SW];
    __shared__ float part[SW * 96];
    __shared__ float att[SW][24], mk[SW][NBK];
    __shared__ float lg[SW][144];

    const long rowd0 = (long)s_step * BATCH + b0;
    const int n2 = (tid < 600) ? tid / 100 : 0;
    const int w2 = (tid < 600) ? tid - n2 * 100 : 0;

    // ---- EARLY ISSUE: U gather (consumed in P2, ~5 barriers later) ----
    float uraw[HH][3][SW];
    if (tid < 600) {
#pragma unroll
        for (int h = 0; h < HH; h++) {
            const float* Uh = U + ((long)h * MU + rowd0) * UN2 + n2 * G3;
#pragma unroll
            for (int s = 0; s < SW; s++)
#pragma unroll
                for (int g = 0; g < 3; g++)
                    uraw[h][g][s] = Uh[(long)s * UN2 + g * BS + w2];
        }
    }

    // ---- P0: load state (transposed) + kappa ----
    for (int i = tid; i < SW * NHID; i += 1024) {
        int s = i / NHID, j = i - s * NHID;
        hbT[j][s] = h_prev[(long)(b0 + s) * NHID + j] * masks_t[b0 + s];
    }
    for (int i = tid; i < SW * KAPN; i += 1024) {
        int s = i / KAPN, j = i - s * KAPN;
        kp[s][j] = Kbuf[(rowd0 + s) * KAPN + j];
    }
    __syncthreads();
    // ---- P1: input-attention logits ----
    if (tid < SW * 96) {
        int g = tid >> 2, q = tid & 3;
        int s = g / 24, r = g - s * 24;
        int n = r >> 2, h = r & 3;
        float acc = 0.f;
        int w0 = q * 25;
        for (int w = w0; w < w0 + 25; w++) acc += hbT[n * BS + w][s] * kp[s][h * BS + w];
        part[tid] = acc;
    }
    __syncthreads();
    if (tid < SW * 24) {
        int s = tid / 24, r = tid - s * 24;
        float l = part[tid * 4] + part[tid * 4 + 1] + part[tid * 4 + 2] + part[tid * 4 + 3];
        att[s][r] = sigf(l * 0.125f);        // softmax([l,0])[0] == sigmoid(l)
    }
    __syncthreads();
    if (tid < SW) {
        float a[NBK], av[NBK];
        for (int n = 0; n < NBK; n++) {
            av[n] = 0.25f * (att[tid][n * 4] + att[tid][n * 4 + 1] + att[tid][n * 4 + 2] + att[tid][n * 4 + 3]);
            a[n] = av[n];
        }
        for (int i = 0; i < 4; i++) {
            int mx = i;
            for (int j = i + 1; j < NBK; j++) if (a[j] > a[mx]) mx = j;
            float t = a[i]; a[i] = a[mx]; a[mx] = t;
        }
        float kth = a[3];
        for (int n = 0; n < NBK; n++) mk[tid][n] = (av[n] >= kth) ? 1.f : 0.f;
    }

    // ---- P2: GRU — gi (early-fetched U) + gh (f32x4 Whh4, deep unroll) ----
    if (tid < 600) {
        float gi[3][SW], gh[3][SW];
#pragma unroll
        for (int g = 0; g < 3; g++) {
            float bi = b_ih[n2 * G3 + g * BS + w2];
            float bh = b_hh[n2 * G3 + g * BS + w2];
#pragma unroll
            for (int s = 0; s < SW; s++) { gi[g][s] = bi; gh[g][s] = bh; }
        }
#pragma unroll
        for (int h = 0; h < HH; h++)
#pragma unroll
            for (int s = 0; s < SW; s++) {
                float a = att[s][n2 * 4 + h];
#pragma unroll
                for (int g = 0; g < 3; g++)
                    gi[g][s] += a * uraw[h][g][s];
            }
        const f32x4* Wn4 = ((const f32x4*)Whh4) + (long)n2 * BS * BS + w2;
#pragma unroll 10
        for (int d = 0; d < BS; d++) {
            f32x4 wv = Wn4[(long)d * BS];
            float2 hv = *(const float2*)&hbT[n2 * BS + d][0];
            gh[0][0] += wv[0] * hv.x; gh[0][1] += wv[0] * hv.y;
            gh[1][0] += wv[1] * hv.x; gh[1][1] += wv[1] * hv.y;
            gh[2][0] += wv[2] * hv.x; gh[2][1] += wv[2] * hv.y;
        }
        float2 hnv;
        {
            float rr0 = sigf(gi[0][0] + gh[0][0]);
            float zz0 = sigf(gi[1][0] + gh[1][0]);
            float ng0 = tanhf(gi[2][0] + rr0 * gh[2][0]);
            hnv.x = (1.f - zz0) * ng0 + zz0 * hbT[n2 * BS + w2][0];
            float rr1 = sigf(gi[0][1] + gh[0][1]);
            float zz1 = sigf(gi[1][1] + gh[1][1]);
            float ng1 = tanhf(gi[2][1] + rr1 * gh[2][1]);
            hnv.y = (1.f - zz1) * ng1 + zz1 * hbT[n2 * BS + w2][1];
        }
        *(float2*)&hnT[n2 * BS + w2][0] = hnv;
    }
    __syncthreads();

    // ---- P3: comm projections (direct-L2 Wq/k/v_c, deep unroll) ----
    if (tid < 768) {
        const int mat = tid >> 8, r = tid & 255, ng = r >> 7, c = r & 127;
        const float* W = (mat == 0) ? Wq_c : ((mat == 1) ? Wk_c : Wv_c);
        float acc[3][SW];
#pragma unroll
        for (int j = 0; j < 3; j++)
#pragma unroll
            for (int s = 0; s < SW; s++) acc[j][s] = 0.f;
#pragma unroll 10
        for (int d = 0; d < BS; d++) {
            float wv = W[d * 128 + c];
#pragma unroll
            for (int j = 0; j < 3; j++) {
                float2 hv = *(const float2*)&hnT[(ng * 3 + j) * BS + d][0];
                acc[j][0] += wv * hv.x;
                acc[j][1] += wv * hv.y;
            }
        }
        float (*dst)[768] = (mat == 0) ? qcb : ((mat == 1) ? kcb : vcb);
#pragma unroll
        for (int j = 0; j < 3; j++)
#pragma unroll
            for (int s = 0; s < SW; s++)
                dst[s][(ng * 3 + j) * 128 + c] = acc[j][s];
    }
    __syncthreads();

    // ---- P4: comm attention logits + softmax + co ----
    if (tid < SW * 144) {
        int s = tid / 144, r = tid - s * 144;
        int h = r / 36, r2 = r - h * 36, n = r2 / NBK, m = r2 - n * NBK;
        float sv = 0.f;
#pragma unroll
        for (int e4 = 0; e4 < 8; e4++) {
            f32x4 qv = *(const f32x4*)&qcb[s][n * 128 + h * 32 + e4 * 4];
            f32x4 kv = *(const f32x4*)&kcb[s][m * 128 + h * 32 + e4 * 4];
            sv += qv[0] * kv[0] + qv[1] * kv[1] + qv[2] * kv[2] + qv[3] * kv[3];
        }
        lg[s][r] = sv * 0.17677669529663687f;
    }
    __syncthreads();
    if (tid < SW * 24) {
        int s = tid / 24, r = tid - s * 24;
        float* row = &lg[s][r * NBK];
        float mx = row[0];
        for (int m = 1; m < NBK; m++) mx = fmaxf(mx, row[m]);
        float sv = 0.f;
        for (int m = 0; m < NBK; m++) { row[m] = expf(row[m] - mx); sv += row[m]; }
        float inv = 1.f / sv;
        for (int m = 0; m < NBK; m++) row[m] *= inv;
    }
    __syncthreads();
    for (int idx = tid; idx < SW * 768; idx += 1024) {
        int s = idx / 768, r = idx - s * 768;
        int n = r >> 7, d = r & 127, h = d >> 5;
        float a = 0.f;
#pragma unroll
        for (int m = 0; m < NBK; m++) a += lg[s][h * 36 + n * NBK + m] * vcb[s][m * 128 + d];
        coT[r][s] = a;
    }
    __syncthreads();

    // ---- P5: co @ Wo_c (deep unroll) + masked select ----
    if (tid < 600) {
        float a0 = 0.f, a1 = 0.f;
#pragma unroll 8
        for (int d = 0; d < 128; d++) {
            float wv = Wo_c[d * BS + w2];
            float2 cv = *(const float2*)&coT[n2 * 128 + d][0];
            a0 += wv * cv.x;
            a1 += wv * cv.y;
        }
        float2 res;
        float hc0 = hnT[n2 * BS + w2][0] + a0;
        float hc1 = hnT[n2 * BS + w2][1] + a1;
        res.x = (mk[0][n2] > 0.5f) ? hc0 : hbT[n2 * BS + w2][0];
        res.y = (mk[1][n2] > 0.5f) ? hc1 : hbT[n2 * BS + w2][1];
        *(float2*)&hbT[n2 * BS + w2][0] = res;
    }
    __syncthreads();
    // ---- P6: coalesced global writes ----
    for (int i = tid; i < SW * NHID; i += 1024) {
        int s = i / NHID, j = i - s * NHID;
        h_out[(long)(b0 + s) * NHID + j] = hbT[j][s];
    }
    for (int i = tid; i < SW * DECKP; i += 1024) {
        int s = i / DECKP, col = i - s * DECKP;
        A_dec[(rowd0 + s) * DECKP + col] = f2b(col < NHID ? hbT[col][s] : 0.f);
    }
}

// ===== host launch =====
extern "C" void kernel_launch(void* const* d_in, const int* in_sizes, int n_in,
                              void* d_out, int out_size, void* d_ws, size_t ws_size,
                              hipStream_t stream)
{
    const float* input = (const float*)d_in[0];
    const float* h0    = (const float*)d_in[1];
    const float* masks = (const float*)d_in[2];
    const float* enc_W = (const float*)d_in[3];
    const float* enc_b = (const float*)d_in[4];
    const float* Wq_in = (const float*)d_in[5];
    const float* Wk_in = (const float*)d_in[6];
    const float* Wv_in = (const float*)d_in[7];
    const float* W_ih  = (const float*)d_in[8];
    const float* W_hh  = (const float*)d_in[9];
    const float* b_ih  = (const float*)d_in[10];
    const float* b_hh  = (const float*)d_in[11];
    const float* Wq_c  = (const float*)d_in[12];
    const float* Wk_c  = (const float*)d_in[13];
    const float* Wv_c  = (const float*)d_in[14];
    const float* Wo_c  = (const float*)d_in[15];
    const float* dec_W = (const float*)d_in[16];
    const float* dec_b = (const float*)d_in[17];
    float* out = (float*)d_out;

    const size_t AL = 256;
    auto pad = [&](size_t x) { return (x + AL - 1) & ~(AL - 1); };
    size_t fixedB = pad((size_t)NTOK * CNP * 4)
                  + pad((size_t)NTOK * 256 * 4)
                  + pad((size_t)HH * DK * BS * 4)
                  + pad((size_t)256 * 4)
                  + pad((size_t)CNP * 4)
                  + pad((size_t)NBK * BS * BS * 4 * 4)     // Whh4
                  + pad((size_t)CNP * 3 * KV0 * 2)
                  + pad((size_t)HH * UN2P * 3 * UK0 * 2)
                  + pad((size_t)NTOK * DECKP * 2)
                  + 2 * pad((size_t)BATCH * NHID * 4);
    auto perC = [&](int C) {
        size_t MU = (size_t)C * BATCH;
        return pad(MU * KAPN * 4)
             + pad((size_t)HH * MU * 3 * UK0 * 2)
             + pad((size_t)HH * MU * UN2 * 4)
             + pad(MU * DECKP * 2);
    };
    int C = 8;
    while (C > 1 && fixedB + perC(C) > ws_size) C >>= 1;
    const int MU = C * BATCH;
    const int NCH = T_STEPS / C;

    char* p = (char*)d_ws;
    auto alloc = [&](size_t bytes) { char* r = p; p += pad(bytes); return r; };
    float*          EWfull = (float*)alloc((size_t)NTOK * CNP * 4);
    float*          EWk    = (float*)alloc((size_t)NTOK * 256 * 4);
    float*          WqT    = (float*)alloc((size_t)HH * DK * BS * 4);
    float*          kbf    = (float*)alloc((size_t)256 * 4);
    float*          bias_c = (float*)alloc((size_t)CNP * 4);
    float*          Whh4   = (float*)alloc((size_t)NBK * BS * BS * 4 * 4);
    unsigned short* B_vkap = (unsigned short*)alloc((size_t)CNP * 3 * KV0 * 2);
    unsigned short* B_U    = (unsigned short*)alloc((size_t)HH * UN2P * 3 * UK0 * 2);
    unsigned short* B_dec  = (unsigned short*)alloc((size_t)NTOK * DECKP * 2);
    float*          hA     = (float*)alloc((size_t)BATCH * NHID * 4);
    float*          hB     = (float*)alloc((size_t)BATCH * NHID * 4);
    float*          Kbuf   = (float*)alloc((size_t)MU * KAPN * 4);
    unsigned short* A_U    = (unsigned short*)alloc((size_t)HH * MU * 3 * UK0 * 2);
    float*          Ubuf   = (float*)alloc((size_t)HH * MU * UN2 * 4);
    unsigned short* A_dec  = (unsigned short*)alloc((size_t)MU * DECKP * 2);

    dim3 blk(256);
    ZOff z0 = {1, 0, 0};

    // ---- setup ----
    sgemm<<<dim3(6, 4, 1), blk, 0, stream>>>(
        enc_W, z0, NINP, Wv_in, z0, HH * DV, EWfull, z0, CNP, NTOK, VN, NINP);
    sgemm<<<dim3(4, 4, 1), blk, 0, stream>>>(
        enc_W, z0, NINP, Wk_in, z0, HH * DK, EWk, z0, 256, NTOK, HH * DK, NINP);
    prep_wqt<<<dim3((HH * DK * BS + 255) / 256), blk, 0, stream>>>(Wq_in, WqT);
    prep_whh4<<<dim3((NBK * BS * G3 + 255) / 256), blk, 0, stream>>>(W_hh, Whh4);
    sgemm<<<dim3(2, 4, HH), blk, 0, stream>>>(
        EWk, ZOff{1, DK, 0}, 256, WqT, ZOff{1, (long)DK * BS, 0}, BS,
        EWfull + VN, ZOff{1, BS, 0}, CNP, NTOK, BS, DK);
    bias_k<<<dim3(1), blk, 0, stream>>>(enc_b, Wk_in, kbf);
    bias_c_kernel<<<dim3(3), blk, 0, stream>>>(enc_b, Wv_in, kbf, WqT, bias_c);
    cvt_split_ew<<<dim3((CNP * NTOK + 255) / 256), blk, 0, stream>>>(EWfull, B_vkap);
    cvt_split_bu2<<<dim3((HH * UN2P * UK0 + 255) / 256), blk, 0, stream>>>(W_ih, B_U);
    cvt_dec<<<dim3((NTOK * DECKP + 255) / 256), blk, 0, stream>>>(dec_W, B_dec);

    const float* hp = h0;
    float* hbufs[2] = { hA, hB };
    int t = 0;
    for (int c = 0; c < NCH; c++) {
        // kv + kappa: fp32 input direct (in-reg split3), all-segment staging
        gemm6_kvseg<<<dim3(CNP / 128, MU / 64, 1), blk, 0, stream>>>(
            input + (size_t)c * MU * NTOK, B_vkap, A_U, Kbuf, bias_c, MU);
        // U: z=head, 64x128 tile, all-segment staging
        gemm6_useg<<<dim3(UN2P / 128, MU / 64, HH), blk, 0, stream>>>(
            A_U, (long)MU * 3 * UK0, B_U, (long)UN2P * 3 * UK0,
            Ubuf, (long)MU * UN2, UN2, UN2, UK0);
        for (int s = 0; s < C; s++, t++) {
            float* hout = hbufs[t & 1];
            step_fused<<<dim3(BATCH / SW), dim3(1024), 0, stream>>>(
                hp, masks + (size_t)t * BATCH, Kbuf, Ubuf, b_ih, b_hh, Whh4,
                Wq_c, Wk_c, Wv_c, Wo_c, hout, A_dec, s, MU);
            hp = hout;
        }
        gemm_mfma64<<<dim3(NTOK / 128, MU / 64, 1), blk, 0, stream>>>(
            A_dec, B_dec, out + (size_t)c * MU * NTOK, NTOK, dec_b, DECKP);
    }
}

// Round 18
// 5279.522 us; speedup vs baseline: 1.4200x; 1.0264x over previous
//
#include <hip/hip_runtime.h>
#include <math.h>

#define T_STEPS 128
#define BATCH   512
#define NTOK    512
#define NINP    512
#define NHID    600
#define NBK     6
#define BS      100
#define HH      4
#define DK      64
#define DV      85
#define ATT     340
#define H2      4
#define DK2     32
#define DV2     32
#define G3      300
#define VN      340
#define KAPN    400
#define CN      740
#define CNP     768
#define UN2     1800     // merged U cols per head (6 blocks x 300)
#define UN2P    1920     // padded to 15*128
#define UK0     128
#define KV0     512
#define DECKP   640
#define SW      2        // samples per step-block -> grid 256 = all CUs (measured optimum R14)

typedef __attribute__((ext_vector_type(8))) short short8;
typedef __attribute__((ext_vector_type(4))) short short4v;
typedef __attribute__((ext_vector_type(4))) float f32x4;

typedef __attribute__((address_space(1))) const unsigned int* g1ptr;
typedef __attribute__((address_space(3))) unsigned int* l3ptr;

__device__ __forceinline__ float sigf(float x) { return 1.f / (1.f + expf(-x)); }
__device__ __forceinline__ unsigned short f2b(float f) {
    unsigned u = __float_as_uint(f);
    unsigned r = (u + 0x7fffu + ((u >> 16) & 1u)) >> 16;
    return (unsigned short)r;
}
__device__ __forceinline__ float b2f(unsigned short u) {
    return __uint_as_float(((unsigned)u) << 16);
}
__device__ __forceinline__ void split3(float x, unsigned short& hi,
                                       unsigned short& mid, unsigned short& lo) {
    hi = f2b(x);
    float r1 = x - b2f(hi);
    mid = f2b(r1);
    lo = f2b(r1 - b2f(mid));
}

// Stage a 128x64-short tile into LDS via async global_load_lds (16B/lane).
__device__ __forceinline__ void stage_tile(const unsigned short* __restrict__ gbase,
                                           long rowStride, int m0, int k0,
                                           unsigned short* lds, int tid)
{
    const int w = tid >> 6;
#pragma unroll
    for (int q = 0; q < 4; q++) {
        int idx = (q << 8) + tid;
        int r = idx >> 3, ce = (idx & 7) << 3;
        const unsigned short* g = gbase + (long)(m0 + r) * rowStride + k0 + ce;
        unsigned short* l = lds + q * 2048 + w * 512;   // wave-uniform base
        __builtin_amdgcn_global_load_lds((g1ptr)(const void*)g, (l3ptr)(void*)l, 16, 0, 0);
    }
}
// 64-row variant (2 rounds)
__device__ __forceinline__ void stage_tile64(const unsigned short* __restrict__ gbase,
                                             long rowStride, int m0, int k0,
                                             unsigned short* lds, int tid)
{
    const int w = tid >> 6;
#pragma unroll
    for (int q = 0; q < 2; q++) {
        int idx = (q << 8) + tid;
        int r = idx >> 3, ce = (idx & 7) << 3;
        const unsigned short* g = gbase + (long)(m0 + r) * rowStride + k0 + ce;
        unsigned short* l = lds + q * 2048 + w * 512;
        __builtin_amdgcn_global_load_lds((g1ptr)(const void*)g, (l3ptr)(void*)l, 16, 0, 0);
    }
}

// ===== U GEMM: 64x128 tile, all-segment staging per k0 (96 MFMA / barrier-pair) =====
__global__ __launch_bounds__(256) void gemm6_useg(
    const unsigned short* __restrict__ A, long aZ,
    const unsigned short* __restrict__ B, long bZ,
    float* __restrict__ C, long cZ, int ldc, int Nreal, int K0)
{
    const int bz = blockIdx.z;
    A += (long)bz * aZ;
    B += (long)bz * bZ;
    C += (long)bz * cZ;
    const int LDA = 3 * K0;
    const int m0 = blockIdx.y * 64, n0 = blockIdx.x * 128;
    __shared__ __align__(16) unsigned short As3[3][64 * 64];
    __shared__ __align__(16) unsigned short Bs3[3][128 * 64];
    const int tid = threadIdx.x;
    const int lane = tid & 63;
    const int w = tid >> 6;

    f32x4 acc[4][2];
#pragma unroll
    for (int m = 0; m < 4; m++)
#pragma unroll
        for (int n = 0; n < 2; n++)
#pragma unroll
            for (int v = 0; v < 4; v++) acc[m][n][v] = 0.f;

    const int segA[6] = {0, 0, 1, 0, 2, 1};
    const int segB[6] = {0, 1, 0, 2, 0, 1};
    for (int k0 = 0; k0 < K0; k0 += 64) {
        __syncthreads();
#pragma unroll
        for (int s = 0; s < 3; s++) stage_tile64(A + s * K0, LDA, m0, k0, As3[s], tid);
#pragma unroll
        for (int s = 0; s < 3; s++) stage_tile(B + s * K0, LDA, n0, k0, Bs3[s], tid);
        __syncthreads();
#pragma unroll
        for (int p = 0; p < 6; p++) {
            const unsigned short* Asl = As3[segA[p]];
            const unsigned short* Bsl = Bs3[segB[p]];
#pragma unroll
            for (int kk = 0; kk < 2; kk++) {
                short8 af[4], bfr[2];
#pragma unroll
                for (int m = 0; m < 4; m++)
                    af[m] = *(const short8*)&Asl[(m * 16 + (lane & 15)) * 64 + kk * 32 + (lane >> 4) * 8];
#pragma unroll
                for (int n = 0; n < 2; n++)
                    bfr[n] = *(const short8*)&Bsl[(w * 32 + n * 16 + (lane & 15)) * 64 + kk * 32 + (lane >> 4) * 8];
#pragma unroll
                for (int m = 0; m < 4; m++)
#pragma unroll
                    for (int n = 0; n < 2; n++)
                        acc[m][n] = __builtin_amdgcn_mfma_f32_16x16x32_bf16(af[m], bfr[n], acc[m][n], 0, 0, 0);
            }
        }
    }
#pragma unroll
    for (int m = 0; m < 4; m++) {
        int rbase = m0 + m * 16 + (lane >> 4) * 4;
#pragma unroll
        for (int n = 0; n < 2; n++) {
            int col = n0 + w * 32 + n * 16 + (lane & 15);
            if (col < Nreal) {
#pragma unroll
                for (int v = 0; v < 4; v++)
                    C[(long)(rbase + v) * ldc + col] = acc[m][n][v];
            }
        }
    }
}

// ===== kv GEMM: A = fp32 input with in-reg split3; 64x128 tile =====
__global__ __launch_bounds__(256) void gemm6_kvseg(
    const float* __restrict__ X,            // [MU][512] fp32 input chunk
    const unsigned short* __restrict__ B,   // [768][3*512] bf16 3-seg
    unsigned short* __restrict__ A_U,       // [4][MU][3*UK0]
    float* __restrict__ Kbuf,               // [MU][400]
    const float* __restrict__ bias, int MU)
{
    const int m0 = blockIdx.y * 64, n0 = blockIdx.x * 128;
    __shared__ __align__(16) unsigned short As3[3][64 * 64];
    __shared__ __align__(16) unsigned short Bs3[3][128 * 64];
    const int tid = threadIdx.x;
    const int lane = tid & 63;
    const int w = tid >> 6;

    f32x4 acc[4][2];
#pragma unroll
    for (int m = 0; m < 4; m++)
#pragma unroll
        for (int n = 0; n < 2; n++)
#pragma unroll
            for (int v = 0; v < 4; v++) acc[m][n][v] = 0.f;

    const int segA[6] = {0, 0, 1, 0, 2, 1};
    const int segB[6] = {0, 1, 0, 2, 0, 1};
    for (int k0 = 0; k0 < KV0; k0 += 64) {
        f32x4 xv[4];
#pragma unroll
        for (int q = 0; q < 4; q++) {
            int idx = (q << 8) + tid;
            int r = idx >> 4, c4 = (idx & 15) << 2;
            xv[q] = *(const f32x4*)&X[(long)(m0 + r) * KV0 + k0 + c4];
        }
        __syncthreads();
#pragma unroll
        for (int s = 0; s < 3; s++) stage_tile(B + s * KV0, 3 * KV0, n0, k0, Bs3[s], tid);
#pragma unroll
        for (int q = 0; q < 4; q++) {
            int idx = (q << 8) + tid;
            int r = idx >> 4, c4 = (idx & 15) << 2;
            short4v hs, ms, ls;
#pragma unroll
            for (int j = 0; j < 4; j++) {
                unsigned short h, m, l;
                split3(xv[q][j], h, m, l);
                hs[j] = (short)h; ms[j] = (short)m; ls[j] = (short)l;
            }
            *(short4v*)&As3[0][r * 64 + c4] = hs;
            *(short4v*)&As3[1][r * 64 + c4] = ms;
            *(short4v*)&As3[2][r * 64 + c4] = ls;
        }
        __syncthreads();
#pragma unroll
        for (int p = 0; p < 6; p++) {
            const unsigned short* Asl = As3[segA[p]];
            const unsigned short* Bsl = Bs3[segB[p]];
#pragma unroll
            for (int kk = 0; kk < 2; kk++) {
                short8 af[4], bfr[2];
#pragma unroll
                for (int m = 0; m < 4; m++)
                    af[m] = *(const short8*)&Asl[(m * 16 + (lane & 15)) * 64 + kk * 32 + (lane >> 4) * 8];
#pragma unroll
                for (int n = 0; n < 2; n++)
                    bfr[n] = *(const short8*)&Bsl[(w * 32 + n * 16 + (lane & 15)) * 64 + kk * 32 + (lane >> 4) * 8];
#pragma unroll
                for (int m = 0; m < 4; m++)
#pragma unroll
                    for (int n = 0; n < 2; n++)
                        acc[m][n] = __builtin_amdgcn_mfma_f32_16x16x32_bf16(af[m], bfr[n], acc[m][n], 0, 0, 0);
            }
        }
    }
#pragma unroll
    for (int m = 0; m < 4; m++) {
        int rbase = m0 + m * 16 + (lane >> 4) * 4;
#pragma unroll
        for (int n = 0; n < 2; n++) {
            int col = n0 + w * 32 + n * 16 + (lane & 15);
            if (col < CN) {
                float bv = bias[col];
                if (col < VN) {
                    int h = col / DV, kk2 = col - h * DV;
#pragma unroll
                    for (int v = 0; v < 4; v++) {
                        float val = acc[m][n][v] + bv;
                        unsigned short hi, mid, lo;
                        split3(val, hi, mid, lo);
                        long base = ((long)h * MU + (rbase + v)) * (3 * UK0) + kk2;
                        A_U[base] = hi;
                        A_U[base + UK0] = mid;
                        A_U[base + 2 * UK0] = lo;
                    }
                } else {
                    int kc = col - VN;
#pragma unroll
                    for (int v = 0; v < 4; v++)
                        Kbuf[(long)(rbase + v) * KAPN + kc] = acc[m][n][v] + bv;
                }
            }
        }
    }
}

// ===== plain bf16 MFMA GEMM, 64x128 tile (decoder) =====
__global__ __launch_bounds__(256) void gemm_mfma64(
    const unsigned short* __restrict__ A,
    const unsigned short* __restrict__ B,
    float* __restrict__ C, int ldc,
    const float* __restrict__ bias, int Kp)
{
    const int m0 = blockIdx.y * 64, n0 = blockIdx.x * 128;
    __shared__ __align__(16) unsigned short As[64 * 64];
    __shared__ __align__(16) unsigned short Bs[128 * 64];
    const int tid = threadIdx.x;
    const int lane = tid & 63;
    const int w = tid >> 6;

    f32x4 acc[4][2];
#pragma unroll
    for (int m = 0; m < 4; m++)
#pragma unroll
        for (int n = 0; n < 2; n++)
#pragma unroll
            for (int v = 0; v < 4; v++) acc[m][n][v] = 0.f;

    for (int k0 = 0; k0 < Kp; k0 += 64) {
        __syncthreads();
        stage_tile64(A, Kp, m0, k0, As, tid);
        stage_tile(B, Kp, n0, k0, Bs, tid);
        __syncthreads();
#pragma unroll
        for (int kk = 0; kk < 2; kk++) {
            short8 af[4], bfr[2];
#pragma unroll
            for (int m = 0; m < 4; m++)
                af[m] = *(const short8*)&As[(m * 16 + (lane & 15)) * 64 + kk * 32 + (lane >> 4) * 8];
#pragma unroll
            for (int n = 0; n < 2; n++)
                bfr[n] = *(const short8*)&Bs[(w * 32 + n * 16 + (lane & 15)) * 64 + kk * 32 + (lane >> 4) * 8];
#pragma unroll
            for (int m = 0; m < 4; m++)
#pragma unroll
                for (int n = 0; n < 2; n++)
                    acc[m][n] = __builtin_amdgcn_mfma_f32_16x16x32_bf16(af[m], bfr[n], acc[m][n], 0, 0, 0);
        }
    }
#pragma unroll
    for (int m = 0; m < 4; m++) {
        int rbase = m0 + m * 16 + (lane >> 4) * 4;
#pragma unroll
        for (int n = 0; n < 2; n++) {
            int col = n0 + w * 32 + n * 16 + (lane & 15);
            float bv = bias ? bias[col] : 0.f;
#pragma unroll
            for (int v = 0; v < 4; v++)
                C[(long)(rbase + v) * ldc + col] = acc[m][n][v] + bv;
        }
    }
}

// ===== setup: KW = Wk_in @ WqT  (KW[k][h*100+w], k<512) =====
__global__ __launch_bounds__(256) void kw_kernel(const float* __restrict__ Wk_in,
                                                 const float* __restrict__ WqT,
                                                 float* __restrict__ KW)
{
    int idx = blockIdx.x * 256 + threadIdx.x;
    if (idx >= NTOK * KAPN) return;
    int k = idx / KAPN, r = idx - k * KAPN;
    int h = r / BS, w = r - h * BS;
    float acc = 0.f;
#pragma unroll 8
    for (int d = 0; d < DK; d++)
        acc += Wk_in[k * (HH * DK) + h * DK + d] * WqT[(h * DK + d) * BS + w];
    KW[idx] = acc;
}

// ===== setup: P[z] = enc_W[:, z*256:(z+1)*256] @ [Wv_in | KW]  (64x64 tiles) =====
__global__ __launch_bounds__(256) void gemm_ew(const float* __restrict__ enc_W,
                                               const float* __restrict__ Wv,
                                               const float* __restrict__ KW,
                                               float* __restrict__ P)
{
    const int m0 = blockIdx.y * 64, j0 = blockIdx.x * 64, kb = blockIdx.z * 256;
    float* Pz = P + (long)blockIdx.z * NTOK * CNP;
    __shared__ float As[16][68];
    __shared__ float Bs[16][68];
    const int tid = threadIdx.x;
    const int tm = tid >> 4, tn = tid & 15;

    float acc[4][4];
#pragma unroll
    for (int i = 0; i < 4; i++)
#pragma unroll
        for (int j = 0; j < 4; j++) acc[i][j] = 0.f;

    for (int k0 = 0; k0 < 256; k0 += 16) {
        float av[4], bv[4];
#pragma unroll
        for (int e = 0; e < 4; e++) {
            int i2 = (e << 8) + tid;
            int r = i2 >> 4, kk = i2 & 15;
            av[e] = enc_W[(long)(m0 + r) * NINP + kb + k0 + kk];
            int j = i2 & 63, kk2 = i2 >> 6;
            int gj = j0 + j, gk = kb + k0 + kk2;
            float b;
            if (gj < VN) b = Wv[gk * (HH * DV) + gj];
            else if (gj < CN) b = KW[gk * KAPN + (gj - VN)];
            else b = 0.f;
            bv[e] = b;
        }
        __syncthreads();
#pragma unroll
        for (int e = 0; e < 4; e++) {
            int i2 = (e << 8) + tid;
            As[i2 & 15][i2 >> 4] = av[e];
            Bs[i2 >> 6][i2 & 63] = bv[e];
        }
        __syncthreads();
#pragma unroll
        for (int kk = 0; kk < 16; kk++) {
            float a[4], b[4];
#pragma unroll
            for (int i = 0; i < 4; i++) a[i] = As[kk][tm * 4 + i];
#pragma unroll
            for (int j = 0; j < 4; j++) b[j] = Bs[kk][tn * 4 + j];
#pragma unroll
            for (int i = 0; i < 4; i++)
#pragma unroll
                for (int j = 0; j < 4; j++)
                    acc[i][j] += a[i] * b[j];
        }
        __syncthreads();
    }
#pragma unroll
    for (int i = 0; i < 4; i++)
#pragma unroll
        for (int j = 0; j < 4; j++)
            Pz[(long)(m0 + tm * 4 + i) * CNP + j0 + tn * 4 + j] = acc[i][j];
}

// ===== prep kernels =====
__global__ __launch_bounds__(256) void prep_wqt(const float* __restrict__ Wq_in,
                                                float* __restrict__ WqT)
{
    int idx = blockIdx.x * 256 + threadIdx.x;
    if (idx >= HH * DK * BS) return;
    int h = idx / (DK * BS), r = idx - h * DK * BS, d = r / BS, w = r - d * BS;
    WqT[idx] = Wq_in[w * (HH * DK) + h * DK + d];
}

// W_hh[n][d][g*100+w] -> Whh4[n][d][w][4]
__global__ __launch_bounds__(256) void prep_whh4(const float* __restrict__ W_hh,
                                                 float* __restrict__ Whh4)
{
    int idx = blockIdx.x * 256 + threadIdx.x;
    if (idx >= NBK * BS * G3) return;
    int n = idx / (BS * G3), r = idx - n * (BS * G3);
    int d = r / G3, e = r - d * G3;
    int g = e / BS, w = e - g * BS;
    Whh4[(((long)n * BS + d) * BS + w) * 4 + g] = W_hh[idx];
}

__global__ __launch_bounds__(256) void bias_k(const float* __restrict__ enc_b,
                                              const float* __restrict__ Wk,
                                              float* __restrict__ kbf)
{
    int j = threadIdx.x;
    if (j >= HH * DK) return;
    float acc = 0.f;
    for (int d = 0; d < NINP; d++) acc += enc_b[d] * Wk[d * (HH * DK) + j];
    kbf[j] = acc;
}

__global__ __launch_bounds__(256) void bias_c_kernel(const float* __restrict__ enc_b,
                                                     const float* __restrict__ Wv,
                                                     const float* __restrict__ kbf,
                                                     const float* __restrict__ WqT,
                                                     float* __restrict__ bias_c)
{
    int j = blockIdx.x * 256 + threadIdx.x;
    if (j >= CNP) return;
    float acc = 0.f;
    if (j < VN) {
        for (int d = 0; d < NINP; d++) acc += enc_b[d] * Wv[d * (HH * DV) + j];
    } else if (j < CN) {
        int r = j - VN;
        int h = r / BS, w = r - h * BS;
        for (int d = 0; d < DK; d++)
            acc += kbf[h * DK + d] * WqT[(h * DK + d) * BS + w];
    }
    bias_c[j] = acc;
}

__global__ __launch_bounds__(256) void cvt_dec(const float* __restrict__ dec_W,
                                               unsigned short* __restrict__ dst)
{
    int idx = blockIdx.x * 256 + threadIdx.x;
    if (idx >= NTOK * DECKP) return;
    int n = idx / DECKP, k = idx - n * DECKP;
    dst[idx] = f2b(k < NHID ? dec_W[k * NTOK + n] : 0.f);
}

// B_vkap from P0+P1 (deterministic fixed-order sum)
__global__ __launch_bounds__(256) void cvt_split_ew(const float* __restrict__ P,
                                                    unsigned short* __restrict__ dst)
{
    int idx = blockIdx.x * 256 + threadIdx.x;
    if (idx >= CNP * NTOK) return;
    int n = idx / NTOK, k = idx - n * NTOK;
    float x = 0.f;
    if (n < CN)
        x = P[(long)k * CNP + n] + P[(long)NTOK * CNP + (long)k * CNP + n];
    unsigned short hi, mid, lo;
    split3(x, hi, mid, lo);
    long base = (long)n * (3 * KV0) + k;
    dst[base] = hi;
    dst[base + KV0] = mid;
    dst[base + 2 * KV0] = lo;
}

// W_ih -> B_U2: [4][1920][3*128]; col j = n*300 + e
__global__ __launch_bounds__(256) void cvt_split_bu2(const float* __restrict__ W_ih,
                                                     unsigned short* __restrict__ dst)
{
    int idx = blockIdx.x * 256 + threadIdx.x;
    if (idx >= HH * UN2P * UK0) return;
    int h = idx / (UN2P * UK0), r = idx - h * (UN2P * UK0);
    int j = r / UK0, kk = r - j * UK0;
    float x = 0.f;
    if (kk < DV && j < UN2) {
        int n = j / G3, e = j - n * G3;
        x = W_ih[((long)n * ATT + h * DV + kk) * G3 + e];
    }
    unsigned short hi, mid, lo;
    split3(x, hi, mid, lo);
    long base = ((long)h * UN2P + j) * (3 * UK0) + kk;
    dst[base] = hi;
    dst[base + UK0] = mid;
    dst[base + 2 * UK0] = lo;
}

// ===== step kernel (R14-proven optimum): SW=2, 1024 threads, grid 256 =====
__global__ __launch_bounds__(1024) void step_fused(
    const float* __restrict__ h_prev,       // [512,600]
    const float* __restrict__ masks_t,      // [512]
    const float* __restrict__ Kbuf,         // [MU,400]
    const float* __restrict__ U,            // [4,MU,1800]
    const float* __restrict__ b_ih, const float* __restrict__ b_hh,
    const float* __restrict__ Whh4,         // [6][100][100][4]
    const float* __restrict__ Wq_c, const float* __restrict__ Wk_c,
    const float* __restrict__ Wv_c, const float* __restrict__ Wo_c,
    float* __restrict__ h_out,              // [512,600]
    unsigned short* __restrict__ A_dec,     // [MU,640] bf16
    int s_step, int MU)
{
    const int b0 = blockIdx.x * SW, tid = threadIdx.x;
    __shared__ __align__(16) float hbT[NHID][SW];
    __shared__ __align__(16) float hnT[NHID][SW];
    __shared__ __align__(16) float kp[SW][KAPN];
    __shared__ __align__(16) float qcb[SW][768], kcb[SW][768], vcb[SW][768];
    __shared__ __align__(16) float coT[NBK * 128][SW];
    __shared__ float part[SW * 96];
    __shared__ float att[SW][24], mk[SW][NBK];
    __shared__ float lg[SW][144];

    const long rowd0 = (long)s_step * BATCH + b0;
    const int n2 = (tid < 600) ? tid / 100 : 0;
    const int w2 = (tid < 600) ? tid - n2 * 100 : 0;

    // ---- EARLY ISSUE: U gather (consumed in P2, ~5 barriers later) ----
    float uraw[HH][3][SW];
    if (tid < 600) {
#pragma unroll
        for (int h = 0; h < HH; h++) {
            const float* Uh = U + ((long)h * MU + rowd0) * UN2 + n2 * G3;
#pragma unroll
            for (int s = 0; s < SW; s++)
#pragma unroll
                for (int g = 0; g < 3; g++)
                    uraw[h][g][s] = Uh[(long)s * UN2 + g * BS + w2];
        }
    }

    // ---- P0: load state (transposed) + kappa ----
    for (int i = tid; i < SW * NHID; i += 1024) {
        int s = i / NHID, j = i - s * NHID;
        hbT[j][s] = h_prev[(long)(b0 + s) * NHID + j] * masks_t[b0 + s];
    }
    for (int i = tid; i < SW * KAPN; i += 1024) {
        int s = i / KAPN, j = i - s * KAPN;
        kp[s][j] = Kbuf[(rowd0 + s) * KAPN + j];
    }
    __syncthreads();
    // ---- P1: input-attention logits ----
    if (tid < SW * 96) {
        int g = tid >> 2, q = tid & 3;
        int s = g / 24, r = g - s * 24;
        int n = r >> 2, h = r & 3;
        float acc = 0.f;
        int w0 = q * 25;
        for (int w = w0; w < w0 + 25; w++) acc += hbT[n * BS + w][s] * kp[s][h * BS + w];
        part[tid] = acc;
    }
    __syncthreads();
    if (tid < SW * 24) {
        int s = tid / 24, r = tid - s * 24;
        float l = part[tid * 4] + part[tid * 4 + 1] + part[tid * 4 + 2] + part[tid * 4 + 3];
        att[s][r] = sigf(l * 0.125f);        // softmax([l,0])[0] == sigmoid(l)
    }
    __syncthreads();
    if (tid < SW) {
        float a[NBK], av[NBK];
        for (int n = 0; n < NBK; n++) {
            av[n] = 0.25f * (att[tid][n * 4] + att[tid][n * 4 + 1] + att[tid][n * 4 + 2] + att[tid][n * 4 + 3]);
            a[n] = av[n];
        }
        for (int i = 0; i < 4; i++) {
            int mx = i;
            for (int j = i + 1; j < NBK; j++) if (a[j] > a[mx]) mx = j;
            float t = a[i]; a[i] = a[mx]; a[mx] = t;
        }
        float kth = a[3];
        for (int n = 0; n < NBK; n++) mk[tid][n] = (av[n] >= kth) ? 1.f : 0.f;
    }

    // ---- P2: GRU — gi (early-fetched U) + gh (f32x4 Whh4, deep unroll) ----
    if (tid < 600) {
        float gi[3][SW], gh[3][SW];
#pragma unroll
        for (int g = 0; g < 3; g++) {
            float bi = b_ih[n2 * G3 + g * BS + w2];
            float bh = b_hh[n2 * G3 + g * BS + w2];
#pragma unroll
            for (int s = 0; s < SW; s++) { gi[g][s] = bi; gh[g][s] = bh; }
        }
#pragma unroll
        for (int h = 0; h < HH; h++)
#pragma unroll
            for (int s = 0; s < SW; s++) {
                float a = att[s][n2 * 4 + h];
#pragma unroll
                for (int g = 0; g < 3; g++)
                    gi[g][s] += a * uraw[h][g][s];
            }
        const f32x4* Wn4 = ((const f32x4*)Whh4) + (long)n2 * BS * BS + w2;
#pragma unroll 10
        for (int d = 0; d < BS; d++) {
            f32x4 wv = Wn4[(long)d * BS];
            float2 hv = *(const float2*)&hbT[n2 * BS + d][0];
            gh[0][0] += wv[0] * hv.x; gh[0][1] += wv[0] * hv.y;
            gh[1][0] += wv[1] * hv.x; gh[1][1] += wv[1] * hv.y;
            gh[2][0] += wv[2] * hv.x; gh[2][1] += wv[2] * hv.y;
        }
        float2 hnv;
        {
            float rr0 = sigf(gi[0][0] + gh[0][0]);
            float zz0 = sigf(gi[1][0] + gh[1][0]);
            float ng0 = tanhf(gi[2][0] + rr0 * gh[2][0]);
            hnv.x = (1.f - zz0) * ng0 + zz0 * hbT[n2 * BS + w2][0];
            float rr1 = sigf(gi[0][1] + gh[0][1]);
            float zz1 = sigf(gi[1][1] + gh[1][1]);
            float ng1 = tanhf(gi[2][1] + rr1 * gh[2][1]);
            hnv.y = (1.f - zz1) * ng1 + zz1 * hbT[n2 * BS + w2][1];
        }
        *(float2*)&hnT[n2 * BS + w2][0] = hnv;
    }
    __syncthreads();

    // ---- P3: comm projections (direct-L2 Wq/k/v_c, deep unroll) ----
    if (tid < 768) {
        const int mat = tid >> 8, r = tid & 255, ng = r >> 7, c = r & 127;
        const float* W = (mat == 0) ? Wq_c : ((mat == 1) ? Wk_c : Wv_c);
        float acc[3][SW];
#pragma unroll
        for (int j = 0; j < 3; j++)
#pragma unroll
            for (int s = 0; s < SW; s++) acc[j][s] = 0.f;
#pragma unroll 10
        for (int d = 0; d < BS; d++) {
            float wv = W[d * 128 + c];
#pragma unroll
            for (int j = 0; j < 3; j++) {
                float2 hv = *(const float2*)&hnT[(ng * 3 + j) * BS + d][0];
                acc[j][0] += wv * hv.x;
                acc[j][1] += wv * hv.y;
            }
        }
        float (*dst)[768] = (mat == 0) ? qcb : ((mat == 1) ? kcb : vcb);
#pragma unroll
        for (int j = 0; j < 3; j++)
#pragma unroll
            for (int s = 0; s < SW; s++)
                dst[s][(ng * 3 + j) * 128 + c] = acc[j][s];
    }
    __syncthreads();

    // ---- P4: comm attention logits + softmax + co ----
    if (tid < SW * 144) {
        int s = tid / 144, r = tid - s * 144;
        int h = r / 36, r2 = r - h * 36, n = r2 / NBK, m = r2 - n * NBK;
        float sv = 0.f;
#pragma unroll
        for (int e4 = 0; e4 < 8; e4++) {
            f32x4 qv = *(const f32x4*)&qcb[s][n * 128 + h * 32 + e4 * 4];
            f32x4 kv = *(const f32x4*)&kcb[s][m * 128 + h * 32 + e4 * 4];
            sv += qv[0] * kv[0] + qv[1] * kv[1] + qv[2] * kv[2] + qv[3] * kv[3];
        }
        lg[s][r] = sv * 0.17677669529663687f;
    }
    __syncthreads();
    if (tid < SW * 24) {
        int s = tid / 24, r = tid - s * 24;
        float* row = &lg[s][r * NBK];
        float mx = row[0];
        for (int m = 1; m < NBK; m++) mx = fmaxf(mx, row[m]);
        float sv = 0.f;
        for (int m = 0; m < NBK; m++) { row[m] = expf(row[m] - mx); sv += row[m]; }
        float inv = 1.f / sv;
        for (int m = 0; m < NBK; m++) row[m] *= inv;
    }
    __syncthreads();
    for (int idx = tid; idx < SW * 768; idx += 1024) {
        int s = idx / 768, r = idx - s * 768;
        int n = r >> 7, d = r & 127, h = d >> 5;
        float a = 0.f;
#pragma unroll
        for (int m = 0; m < NBK; m++) a += lg[s][h * 36 + n * NBK + m] * vcb[s][m * 128 + d];
        coT[r][s] = a;
    }
    __syncthreads();

    // ---- P5: co @ Wo_c (deep unroll) + masked select ----
    if (tid < 600) {
        float a0 = 0.f, a1 = 0.f;
#pragma unroll 8
        for (int d = 0; d < 128; d++) {
            float wv = Wo_c[d * BS + w2];
            float2 cv = *(const float2*)&coT[n2 * 128 + d][0];
            a0 += wv * cv.x;
            a1 += wv * cv.y;
        }
        float2 res;
        float hc0 = hnT[n2 * BS + w2][0] + a0;
        float hc1 = hnT[n2 * BS + w2][1] + a1;
        res.x = (mk[0][n2] > 0.5f) ? hc0 : hbT[n2 * BS + w2][0];
        res.y = (mk[1][n2] > 0.5f) ? hc1 : hbT[n2 * BS + w2][1];
        *(float2*)&hbT[n2 * BS + w2][0] = res;
    }
    __syncthreads();
    // ---- P6: coalesced global writes ----
    for (int i = tid; i < SW * NHID; i += 1024) {
        int s = i / NHID, j = i - s * NHID;
        h_out[(long)(b0 + s) * NHID + j] = hbT[j][s];
    }
    for (int i = tid; i < SW * DECKP; i += 1024) {
        int s = i / DECKP, col = i - s * DECKP;
        A_dec[(rowd0 + s) * DECKP + col] = f2b(col < NHID ? hbT[col][s] : 0.f);
    }
}

// ===== host launch =====
extern "C" void kernel_launch(void* const* d_in, const int* in_sizes, int n_in,
                              void* d_out, int out_size, void* d_ws, size_t ws_size,
                              hipStream_t stream)
{
    const float* input = (const float*)d_in[0];
    const float* h0    = (const float*)d_in[1];
    const float* masks = (const float*)d_in[2];
    const float* enc_W = (const float*)d_in[3];
    const float* enc_b = (const float*)d_in[4];
    const float* Wq_in = (const float*)d_in[5];
    const float* Wk_in = (const float*)d_in[6];
    const float* Wv_in = (const float*)d_in[7];
    const float* W_ih  = (const float*)d_in[8];
    const float* W_hh  = (const float*)d_in[9];
    const float* b_ih  = (const float*)d_in[10];
    const float* b_hh  = (const float*)d_in[11];
    const float* Wq_c  = (const float*)d_in[12];
    const float* Wk_c  = (const float*)d_in[13];
    const float* Wv_c  = (const float*)d_in[14];
    const float* Wo_c  = (const float*)d_in[15];
    const float* dec_W = (const float*)d_in[16];
    const float* dec_b = (const float*)d_in[17];
    float* out = (float*)d_out;

    const size_t AL = 256;
    auto pad = [&](size_t x) { return (x + AL - 1) & ~(AL - 1); };
    size_t fixedB = pad((size_t)2 * NTOK * CNP * 4)        // P[2]
                  + pad((size_t)NTOK * KAPN * 4)           // KW
                  + pad((size_t)HH * DK * BS * 4)
                  + pad((size_t)256 * 4)
                  + pad((size_t)CNP * 4)
                  + pad((size_t)NBK * BS * BS * 4 * 4)     // Whh4
                  + pad((size_t)CNP * 3 * KV0 * 2)
                  + pad((size_t)HH * UN2P * 3 * UK0 * 2)
                  + pad((size_t)NTOK * DECKP * 2)
                  + 2 * pad((size_t)BATCH * NHID * 4);
    auto perC = [&](int C) {
        size_t MU = (size_t)C * BATCH;
        return pad(MU * KAPN * 4)
             + pad((size_t)HH * MU * 3 * UK0 * 2)
             + pad((size_t)HH * MU * UN2 * 4)
             + pad(MU * DECKP * 2);
    };
    int C = 8;
    while (C > 1 && fixedB + perC(C) > ws_size) C >>= 1;
    const int MU = C * BATCH;
    const int NCH = T_STEPS / C;

    char* p = (char*)d_ws;
    auto alloc = [&](size_t bytes) { char* r = p; p += pad(bytes); return r; };
    float*          Pbuf   = (float*)alloc((size_t)2 * NTOK * CNP * 4);
    float*          KW     = (float*)alloc((size_t)NTOK * KAPN * 4);
    float*          WqT    = (float*)alloc((size_t)HH * DK * BS * 4);
    float*          kbf    = (float*)alloc((size_t)256 * 4);
    float*          bias_c = (float*)alloc((size_t)CNP * 4);
    float*          Whh4   = (float*)alloc((size_t)NBK * BS * BS * 4 * 4);
    unsigned short* B_vkap = (unsigned short*)alloc((size_t)CNP * 3 * KV0 * 2);
    unsigned short* B_U    = (unsigned short*)alloc((size_t)HH * UN2P * 3 * UK0 * 2);
    unsigned short* B_dec  = (unsigned short*)alloc((size_t)NTOK * DECKP * 2);
    float*          hA     = (float*)alloc((size_t)BATCH * NHID * 4);
    float*          hB     = (float*)alloc((size_t)BATCH * NHID * 4);
    float*          Kbuf   = (float*)alloc((size_t)MU * KAPN * 4);
    unsigned short* A_U    = (unsigned short*)alloc((size_t)HH * MU * 3 * UK0 * 2);
    float*          Ubuf   = (float*)alloc((size_t)HH * MU * UN2 * 4);
    unsigned short* A_dec  = (unsigned short*)alloc((size_t)MU * DECKP * 2);

    dim3 blk(256);

    // ---- setup (restructured for parallelism) ----
    prep_wqt<<<dim3((HH * DK * BS + 255) / 256), blk, 0, stream>>>(Wq_in, WqT);
    prep_whh4<<<dim3((NBK * BS * G3 + 255) / 256), blk, 0, stream>>>(W_hh, Whh4);
    kw_kernel<<<dim3((NTOK * KAPN + 255) / 256), blk, 0, stream>>>(Wk_in, WqT, KW);
    gemm_ew<<<dim3(CNP / 64, NTOK / 64, 2), blk, 0, stream>>>(enc_W, Wv_in, KW, Pbuf);
    bias_k<<<dim3(1), blk, 0, stream>>>(enc_b, Wk_in, kbf);
    bias_c_kernel<<<dim3(3), blk, 0, stream>>>(enc_b, Wv_in, kbf, WqT, bias_c);
    cvt_split_ew<<<dim3((CNP * NTOK + 255) / 256), blk, 0, stream>>>(Pbuf, B_vkap);
    cvt_split_bu2<<<dim3((HH * UN2P * UK0 + 255) / 256), blk, 0, stream>>>(W_ih, B_U);
    cvt_dec<<<dim3((NTOK * DECKP + 255) / 256), blk, 0, stream>>>(dec_W, B_dec);

    const float* hp = h0;
    float* hbufs[2] = { hA, hB };
    int t = 0;
    for (int c = 0; c < NCH; c++) {
        gemm6_kvseg<<<dim3(CNP / 128, MU / 64, 1), blk, 0, stream>>>(
            input + (size_t)c * MU * NTOK, B_vkap, A_U, Kbuf, bias_c, MU);
        gemm6_useg<<<dim3(UN2P / 128, MU / 64, HH), blk, 0, stream>>>(
            A_U, (long)MU * 3 * UK0, B_U, (long)UN2P * 3 * UK0,
            Ubuf, (long)MU * UN2, UN2, UN2, UK0);
        for (int s = 0; s < C; s++, t++) {
            float* hout = hbufs[t & 1];
            step_fused<<<dim3(BATCH / SW), dim3(1024), 0, stream>>>(
                hp, masks + (size_t)t * BATCH, Kbuf, Ubuf, b_ih, b_hh, Whh4,
                Wq_c, Wk_c, Wv_c, Wo_c, hout, A_dec, s, MU);
            hp = hout;
        }
        gemm_mfma64<<<dim3(NTOK / 128, MU / 64, 1), blk, 0, stream>>>(
            A_dec, B_dec, out + (size_t)c * MU * NTOK, NTOK, dec_b, DECKP);
    }
}